// Round 1
// baseline (593.450 us; speedup 1.0000x reference)
//
#include <hip/hip_runtime.h>
#include <stdint.h>
#include <stddef.h>

typedef __bf16 bf16x8 __attribute__((ext_vector_type(8)));
typedef float  f32x4  __attribute__((ext_vector_type(4)));

#define NIN   784
#define NINP  832    // 784 padded to 13*64
#define NH    1024
#define NE    512
#define ND    64
#define NOUTP 896    // 784 padded to 7*128 (output-column tiles)

// ---------- helpers ----------
static __device__ __forceinline__ unsigned short f2bf(float f) {
  union { float f; unsigned u; } v; v.f = f;
  unsigned r = v.u + 0x7fffu + ((v.u >> 16) & 1u);
  return (unsigned short)(r >> 16);
}

// ---------- cast fp32 -> bf16 with zero padding (rows via gridDim.y) ----------
__global__ void cast_pad(const float* __restrict__ src, unsigned short* __restrict__ dst,
                         int R, int C, int Cp) {
  int r = blockIdx.y;
  int c = blockIdx.x * blockDim.x + threadIdx.x;
  if (c >= Cp) return;
  float v = 0.f;
  if (r < R && c < C) v = src[(size_t)r * C + c];
  dst[(size_t)r * Cp + c] = f2bf(v);
}

// ---------- emb -> bf16 + per-code squared norm ----------
__global__ void emb_prep(const float* __restrict__ emb, unsigned short* __restrict__ ebf,
                         float* __restrict__ cvec) {
  int j = blockIdx.x, l = threadIdx.x;
  float v = emb[j * ND + l];
  ebf[j * ND + l] = f2bf(v);
  float s = v * v;
  #pragma unroll
  for (int off = 32; off > 0; off >>= 1) s += __shfl_down(s, off);
  if (l == 0) cvec[j] = s;
}

// ---------- GEMM: C[M,N] = act(A[M,K] @ B[N,K]^T + bias) ----------
// 128x128 tile, BK=64, 4 waves (2x2 of 64x64), global_load_lds staging.
__device__ __forceinline__ void stage_tile(const unsigned short* __restrict__ src,
                                           int ld, unsigned short* lds, int t) {
  int wave = t >> 6;
  #pragma unroll
  for (int i = 0; i < 4; ++i) {
    int c = i * 256 + t;          // 16B chunk id, 1024 chunks = 128x64 bf16
    int row = c >> 3;
    int col = (c & 7) << 3;
    const unsigned short* g = src + (size_t)row * ld + col;
    unsigned short* l = lds + (size_t)(i * 256 + wave * 64) * 8;  // wave-uniform base; HW adds lane*16
    __builtin_amdgcn_global_load_lds((__attribute__((address_space(1))) void*)g,
                                     (__attribute__((address_space(3))) void*)l,
                                     16, 0, 0);
  }
}

template <int ACT, int OMODE, bool NCHK>   // ACT:0 none,1 relu,2 sigmoid  OMODE:0 f32,1 bf16,2 both
__global__ __launch_bounds__(256, 2)
void gemm_bt(const unsigned short* __restrict__ A,
             const unsigned short* __restrict__ Bm,
             const float* __restrict__ bias,
             float* __restrict__ Cf,
             unsigned short* __restrict__ Cb,
             int M, int N, int K, int ldc) {
  __shared__ unsigned short lsA[128 * 64];
  __shared__ unsigned short lsB[128 * 64];
  const int t = threadIdx.x;
  const int lane = t & 63;
  const int wave = t >> 6;
  const int wr = wave >> 1, wc = wave & 1;
  const int tm = blockIdx.x, tn = blockIdx.y;

  const unsigned short* Ap = A + (size_t)tm * 128 * K;
  const unsigned short* Bp = Bm + (size_t)tn * 128 * K;

  f32x4 acc[4][4] = {};
  const int lr = lane & 15;            // fragment row (A) / col (B)
  const int lk = (lane >> 4) << 3;     // k sub-offset 0,8,16,24

  for (int k0 = 0; k0 < K; k0 += 64) {
    stage_tile(Ap + k0, K, lsA, t);
    stage_tile(Bp + k0, K, lsB, t);
    __syncthreads();                   // drains vmcnt -> LDS tiles ready
    #pragma unroll
    for (int kk = 0; kk < 64; kk += 32) {
      bf16x8 af[4], bfr[4];
      #pragma unroll
      for (int m = 0; m < 4; ++m)
        af[m] = *(const bf16x8*)&lsA[(wr * 64 + m * 16 + lr) * 64 + kk + lk];
      #pragma unroll
      for (int n = 0; n < 4; ++n)
        bfr[n] = *(const bf16x8*)&lsB[(wc * 64 + n * 16 + lr) * 64 + kk + lk];
      #pragma unroll
      for (int m = 0; m < 4; ++m)
        #pragma unroll
        for (int n = 0; n < 4; ++n)
          acc[m][n] = __builtin_amdgcn_mfma_f32_16x16x32_bf16(af[m], bfr[n], acc[m][n], 0, 0, 0);
    }
    __syncthreads();
  }

  // epilogue: C/D layout col=lane&15, row=(lane>>4)*4+j  [HW-verified]
  const int r0 = tm * 128 + wr * 64;
  const int c0 = tn * 128 + wc * 64;
  const int rsub = (lane >> 4) * 4;
  #pragma unroll
  for (int n = 0; n < 4; ++n) {
    int col = c0 + n * 16 + lr;
    if (NCHK && col >= N) continue;
    float bv = bias ? bias[col] : 0.f;
    #pragma unroll
    for (int m = 0; m < 4; ++m) {
      #pragma unroll
      for (int j = 0; j < 4; ++j) {
        int row = r0 + m * 16 + rsub + j;
        float v = acc[m][n][j] + bv;
        if (ACT == 1) v = fmaxf(v, 0.f);
        if (ACT == 2) v = 1.f / (1.f + expf(-v));
        size_t o = (size_t)row * ldc + col;
        if (OMODE == 0) Cf[o] = v;
        else if (OMODE == 1) Cb[o] = f2bf(v);
        else { Cf[o] = v; Cb[o] = f2bf(v); }
      }
    }
  }
}

// ---------- argmin over codes + gather q + loss partial ----------
__global__ __launch_bounds__(256)
void vq_argmin(const float* __restrict__ zf, const float* __restrict__ scores,
               const float* __restrict__ emb, const float* __restrict__ cvec,
               unsigned short* __restrict__ qb, float* __restrict__ lossacc, int nrows) {
  int wave = threadIdx.x >> 6, lane = threadIdx.x & 63;
  float lsum = 0.f;
  for (int r = blockIdx.x * 4 + wave; r < nrows; r += gridDim.x * 4) {
    const float* srow = scores + (size_t)r * NE;
    float best = 3.4e38f; int bidx = 0;
    #pragma unroll
    for (int i = 0; i < 8; ++i) {
      int j = i * 64 + lane;
      float v = cvec[j] - srow[j];     // ||z||^2 term is row-constant: drops from argmin
      if (v < best) { best = v; bidx = j; }
    }
    #pragma unroll
    for (int off = 32; off > 0; off >>= 1) {
      float ov = __shfl_down(best, off);
      int   oi = __shfl_down(bidx, off);
      if (ov < best || (ov == best && oi < bidx)) { best = ov; bidx = oi; }
    }
    bidx = __shfl(bidx, 0);
    float e = emb[bidx * ND + lane];
    float d = e - zf[(size_t)r * ND + lane];
    lsum += d * d;
    qb[(size_t)r * ND + lane] = f2bf(e);
  }
  #pragma unroll
  for (int off = 32; off > 0; off >>= 1) lsum += __shfl_down(lsum, off);
  if (lane == 0) atomicAdd(lossacc, lsum);
}

__global__ void loss_final(const float* __restrict__ acc, float* __restrict__ o, float denom) {
  o[0] = acc[0] * 1.25f / denom;   // code_loss + 0.25*commit_loss, forward-identical
}

// ---------- launch ----------
extern "C" void kernel_launch(void* const* d_in, const int* in_sizes, int n_in,
                              void* d_out, int out_size, void* d_ws, size_t ws_size,
                              hipStream_t stream) {
  const float* x   = (const float*)d_in[0];
  const float* emb = (const float*)d_in[1];
  const float* We1 = (const float*)d_in[2];
  const float* be1 = (const float*)d_in[3];
  const float* We2 = (const float*)d_in[4];
  const float* be2 = (const float*)d_in[5];
  const float* We3 = (const float*)d_in[6];
  const float* be3 = (const float*)d_in[7];
  const float* Wd1 = (const float*)d_in[8];
  const float* bd1 = (const float*)d_in[9];
  const float* Wd2 = (const float*)d_in[10];
  const float* bd2 = (const float*)d_in[11];
  const float* Wd3 = (const float*)d_in[12];
  const float* bd3 = (const float*)d_in[13];

  const int Bn = in_sizes[0] / NIN;              // 32768
  float* out = (float*)d_out;
  float* out_loss = out + (size_t)Bn * NIN;

  char* ws = (char*)d_ws;
  size_t off = 0;
  auto take = [&](size_t bytes) { char* p = ws + off; off += (bytes + 255) & ~(size_t)255; return p; };

  unsigned short* xpad = (unsigned short*)take((size_t)Bn * NINP * 2);
  unsigned short* hA   = (unsigned short*)take((size_t)Bn * NH * 2);   // h1 -> scores(f32) -> h4
  unsigned short* hB   = (unsigned short*)take((size_t)Bn * NH * 2);   // h2 -> h3
  float*          zf   = (float*)take((size_t)Bn * ND * 4);
  unsigned short* zb   = (unsigned short*)take((size_t)Bn * ND * 2);
  unsigned short* qb   = (unsigned short*)take((size_t)Bn * ND * 2);
  unsigned short* we1p = (unsigned short*)take((size_t)NH * NINP * 2);
  unsigned short* we2b = (unsigned short*)take((size_t)NH * NH * 2);
  unsigned short* we3p = (unsigned short*)take((size_t)128 * NH * 2);  // 64 rows + 64 zero rows
  unsigned short* wd1b = (unsigned short*)take((size_t)NH * ND * 2);
  unsigned short* wd2b = (unsigned short*)take((size_t)NH * NH * 2);
  unsigned short* wd3p = (unsigned short*)take((size_t)NOUTP * NH * 2); // 784 rows + 112 zero rows
  unsigned short* embb = (unsigned short*)take((size_t)NE * ND * 2);
  float*          cvec = (float*)take(NE * 4);
  float*          lossa = (float*)take(4);
  float*          scores = (float*)hA;           // reuse: h1 dead after L2

  hipMemsetAsync(lossa, 0, 4, stream);

  cast_pad<<<dim3((NINP + 255) / 256, Bn), 256, 0, stream>>>(x, xpad, Bn, NIN, NINP);
  cast_pad<<<dim3(4, NH), 256, 0, stream>>>(We1, we1p, NH, NIN, NINP);
  cast_pad<<<dim3(4, NH), 256, 0, stream>>>(We2, we2b, NH, NH, NH);
  cast_pad<<<dim3(4, 128), 256, 0, stream>>>(We3, we3p, ND, NH, NH);
  cast_pad<<<dim3(1, NH), 256, 0, stream>>>(Wd1, wd1b, NH, ND, ND);
  cast_pad<<<dim3(4, NH), 256, 0, stream>>>(Wd2, wd2b, NH, NH, NH);
  cast_pad<<<dim3(4, NOUTP), 256, 0, stream>>>(Wd3, wd3p, NIN, NH, NH);
  emb_prep<<<NE, 64, 0, stream>>>(emb, embb, cvec);

  dim3 blk(256);
  // encoder
  gemm_bt<1,1,false><<<dim3(Bn/128, NH/128), blk, 0, stream>>>(xpad, we1p, be1, nullptr, hA, Bn, NH, NINP, NH);
  gemm_bt<1,1,false><<<dim3(Bn/128, NH/128), blk, 0, stream>>>(hA, we2b, be2, nullptr, hB, Bn, NH, NH, NH);
  gemm_bt<0,2,true ><<<dim3(Bn/128, 1      ), blk, 0, stream>>>(hB, we3p, be3, zf, zb, Bn, ND, NH, ND);
  // VQ: scores = z @ emb^T  (bf16 MFMA), then argmin/gather/loss
  gemm_bt<0,0,false><<<dim3(Bn/128, NE/128), blk, 0, stream>>>(zb, embb, nullptr, scores, nullptr, Bn, NE, ND, NE);
  vq_argmin<<<1024, 256, 0, stream>>>(zf, scores, emb, cvec, qb, lossa, Bn);
  // decoder
  gemm_bt<1,1,false><<<dim3(Bn/128, NH/128), blk, 0, stream>>>(qb, wd1b, bd1, nullptr, hB, Bn, NH, ND, NH);
  gemm_bt<1,1,false><<<dim3(Bn/128, NH/128), blk, 0, stream>>>(hB, wd2b, bd2, nullptr, (unsigned short*)hA, Bn, NH, NH, NH);
  gemm_bt<2,0,true ><<<dim3(Bn/128, NOUTP/128), blk, 0, stream>>>((unsigned short*)hA, wd3p, bd3, out, nullptr, Bn, NIN, NH, NIN);

  loss_final<<<1, 1, 0, stream>>>(lossa, out_loss, (float)Bn * ND);
}

// Round 2
// 508.866 us; speedup vs baseline: 1.1662x; 1.1662x over previous
//
#include <hip/hip_runtime.h>
#include <stdint.h>
#include <stddef.h>

typedef __bf16 bf16x8 __attribute__((ext_vector_type(8)));
typedef float  f32x4  __attribute__((ext_vector_type(4)));
typedef unsigned short u16;

#define NIN   784
#define NINP  896    // 784 padded to 14*64 (even K-tile count for 8-phase)
#define NH    1024
#define NE    512
#define ND    64
#define NOUTP 1024   // 784 output rows padded to 4*256 tiles

#define BAR()   asm volatile("s_barrier" ::: "memory")
#define LGKM0() asm volatile("s_waitcnt lgkmcnt(0)" ::: "memory")
#define VM8()   asm volatile("s_waitcnt vmcnt(8)" ::: "memory")
#define VM0()   asm volatile("s_waitcnt vmcnt(0)" ::: "memory")

// ---------- helpers ----------
static __device__ __forceinline__ u16 f2bf(float f) {
  union { float f; unsigned u; } v; v.f = f;
  unsigned r = v.u + 0x7fffu + ((v.u >> 16) & 1u);
  return (u16)(r >> 16);
}

// ---------- cast fp32 -> bf16 with zero padding, float4 vectorized ----------
__global__ void cast_pad4(const float* __restrict__ src, u16* __restrict__ dst,
                          int R, int C, int Cp) {
  int r = blockIdx.y;
  int c4 = (blockIdx.x * blockDim.x + threadIdx.x) * 4;
  if (c4 >= Cp) return;
  ushort4 o = {0, 0, 0, 0};
  if (r < R && c4 < C) {           // C,Cp multiples of 4
    const float4 v = *(const float4*)&src[(size_t)r * C + c4];
    o.x = f2bf(v.x); o.y = f2bf(v.y); o.z = f2bf(v.z); o.w = f2bf(v.w);
  }
  *(ushort4*)&dst[(size_t)r * Cp + c4] = o;
}

// ---------- emb -> bf16 + per-code squared norm ----------
__global__ void emb_prep(const float* __restrict__ emb, u16* __restrict__ ebf,
                         float* __restrict__ cvec) {
  int j = blockIdx.x, l = threadIdx.x;
  float v = emb[j * ND + l];
  ebf[j * ND + l] = f2bf(v);
  float s = v * v;
  #pragma unroll
  for (int off = 32; off > 0; off >>= 1) s += __shfl_down(s, off);
  if (l == 0) cvec[j] = s;
}

// =========================================================================
// 128x128-tile GEMM (m97 structure) — used for the small/thin GEMMs
// =========================================================================
__device__ __forceinline__ void stage_tile(const u16* __restrict__ src,
                                           int ld, u16* lds, int t) {
  int wave = t >> 6;
  #pragma unroll
  for (int i = 0; i < 4; ++i) {
    int c = i * 256 + t;
    int row = c >> 3;
    int col = (c & 7) << 3;
    const u16* g = src + (size_t)row * ld + col;
    u16* l = lds + (size_t)(i * 256 + wave * 64) * 8;
    __builtin_amdgcn_global_load_lds((__attribute__((address_space(1))) void*)g,
                                     (__attribute__((address_space(3))) void*)l,
                                     16, 0, 0);
  }
}

template <int ACT, int OMODE, bool NCHK>   // ACT:0 none,1 relu,2 sigmoid  OMODE:0 f32,1 bf16,2 both
__global__ __launch_bounds__(256, 2)
void gemm_bt(const u16* __restrict__ A,
             const u16* __restrict__ Bm,
             const float* __restrict__ bias,
             float* __restrict__ Cf,
             u16* __restrict__ Cb,
             int M, int N, int K, int ldc) {
  __shared__ u16 lsA[128 * 64];
  __shared__ u16 lsB[128 * 64];
  const int t = threadIdx.x;
  const int lane = t & 63;
  const int wave = t >> 6;
  const int wr = wave >> 1, wc = wave & 1;
  const int tm = blockIdx.x, tn = blockIdx.y;

  const u16* Ap = A + (size_t)tm * 128 * K;
  const u16* Bp = Bm + (size_t)tn * 128 * K;

  f32x4 acc[4][4] = {};
  const int lr = lane & 15;
  const int lk = (lane >> 4) << 3;

  for (int k0 = 0; k0 < K; k0 += 64) {
    stage_tile(Ap + k0, K, lsA, t);
    stage_tile(Bp + k0, K, lsB, t);
    __syncthreads();
    #pragma unroll
    for (int kk = 0; kk < 64; kk += 32) {
      bf16x8 af[4], bfr[4];
      #pragma unroll
      for (int m = 0; m < 4; ++m)
        af[m] = *(const bf16x8*)&lsA[(wr * 64 + m * 16 + lr) * 64 + kk + lk];
      #pragma unroll
      for (int n = 0; n < 4; ++n)
        bfr[n] = *(const bf16x8*)&lsB[(wc * 64 + n * 16 + lr) * 64 + kk + lk];
      #pragma unroll
      for (int m = 0; m < 4; ++m)
        #pragma unroll
        for (int n = 0; n < 4; ++n)
          acc[m][n] = __builtin_amdgcn_mfma_f32_16x16x32_bf16(af[m], bfr[n], acc[m][n], 0, 0, 0);
    }
    __syncthreads();
  }

  const int r0 = tm * 128 + wr * 64;
  const int c0 = tn * 128 + wc * 64;
  const int rsub = (lane >> 4) * 4;
  float bv[4];
  #pragma unroll
  for (int n = 0; n < 4; ++n) {
    int col = c0 + n * 16 + lr;
    bv[n] = (!NCHK || col < N) ? (bias ? bias[col] : 0.f) : 0.f;
  }
  // row-major store order (n innermost) for write-combining
  #pragma unroll
  for (int m = 0; m < 4; ++m)
    #pragma unroll
    for (int j = 0; j < 4; ++j) {
      int row = r0 + m * 16 + rsub + j;
      #pragma unroll
      for (int n = 0; n < 4; ++n) {
        int col = c0 + n * 16 + lr;
        if (NCHK && col >= N) continue;
        float v = acc[m][n][j] + bv[n];
        if (ACT == 1) v = fmaxf(v, 0.f);
        if (ACT == 2) v = 1.f / (1.f + __expf(-v));
        size_t o = (size_t)row * ldc + col;
        if (OMODE == 0) Cf[o] = v;
        else if (OMODE == 1) Cb[o] = f2bf(v);
        else { Cf[o] = v; Cb[o] = f2bf(v); }
      }
    }
}

// =========================================================================
// 256x256-tile, BK=64, 8-wave, 8-phase GEMM (T1+T2+T3+T4+T5 stack)
// LDS swizzle: stored[r][c16] = data[r][c16 ^ (r&7)]  (involution, both sides)
// =========================================================================
__device__ __forceinline__ void stage256(const u16* __restrict__ src, int ldk,
                                         u16* dstmat, int w, int lane) {
  #pragma unroll
  for (int i = 0; i < 4; ++i) {
    int row = i * 64 + w * 8 + (lane >> 3);
    int gc  = (lane & 7) ^ (lane >> 3);          // pre-swizzled global source
    const u16* g = src + (size_t)row * ldk + gc * 8;
    u16* l = dstmat + (size_t)(i * 512 + w * 64) * 8;  // linear LDS dest (+lane*16 by HW)
    __builtin_amdgcn_global_load_lds((__attribute__((address_space(1))) void*)g,
                                     (__attribute__((address_space(3))) void*)l,
                                     16, 0, 0);
  }
}

template <int S>
__device__ __forceinline__ void ldAT(bf16x8 (&af)[4][2], const u16* mat,
                                     int wr, int lr, int hi) {
  #pragma unroll
  for (int m = 0; m < 4; ++m)
    #pragma unroll
    for (int e = 0; e < 2; ++e) {
      int row = wr * 128 + S * 64 + m * 16 + lr;
      int c = (e * 4 + hi) ^ (lr & 7);           // swizzled read
      af[m][e] = *(const bf16x8*)&mat[row * 64 + c * 8];
    }
}

template <int S>
__device__ __forceinline__ void ldBT(bf16x8 (&bq)[2][2][2], const u16* mat,
                                     int wc, int lr, int hi) {
  #pragma unroll
  for (int f = 0; f < 2; ++f)
    #pragma unroll
    for (int e = 0; e < 2; ++e) {
      int row = wc * 64 + S * 32 + f * 16 + lr;
      int c = (e * 4 + hi) ^ (lr & 7);
      bq[S][f][e] = *(const bf16x8*)&mat[row * 64 + c * 8];
    }
}

template <int MS, int NS>
__device__ __forceinline__ void quadT(f32x4 (&acc)[8][4], bf16x8 (&af)[4][2],
                                      bf16x8 (&bq)[2][2][2]) {
  __builtin_amdgcn_s_setprio(1);
  #pragma unroll
  for (int m = 0; m < 4; ++m)
    #pragma unroll
    for (int f = 0; f < 2; ++f)
      #pragma unroll
      for (int e = 0; e < 2; ++e)
        acc[MS * 4 + m][NS * 2 + f] = __builtin_amdgcn_mfma_f32_16x16x32_bf16(
            af[m][e], bq[NS][f][e], acc[MS * 4 + m][NS * 2 + f], 0, 0, 0);
  __builtin_amdgcn_s_setprio(0);
}

template <int ACT, int OMODE, bool NCHK>
__global__ __launch_bounds__(512, 2)
void gemm256(const u16* __restrict__ A, const u16* __restrict__ Bm,
             const float* __restrict__ bias, float* __restrict__ Cf,
             u16* __restrict__ Cb, int M, int N, int K, int ldc, int mtiles) {
  __shared__ u16 lds[2][2][256 * 64];    // [dbuf][A/B][.]  128 KiB
  const int tid  = threadIdx.x;
  const int lane = tid & 63;
  const int w    = tid >> 6;             // 0..7
  const int wr   = w >> 2, wc = w & 3;   // 2x4 wave grid, per-wave 128x64 out
  const int lr   = lane & 15, hi = lane >> 4;

  // XCD-aware bijective swizzle (gridDim.x % 8 == 0 for all our launches)
  int nwg = gridDim.x, cpx = nwg >> 3, b = blockIdx.x;
  int sb = (b & 7) * cpx + (b >> 3);
  int tm = sb % mtiles, tn = sb / mtiles;

  const u16* Ap = A + (size_t)tm * 256 * K;
  const u16* Bp = Bm + (size_t)tn * 256 * K;
  const int NT = K >> 6;                 // >= 2 for all uses

  f32x4 acc[8][4] = {};
  bf16x8 af[4][2], bq[2][2][2];

  // prologue: stage tiles 0,1 ; wait for tile 0 (16 issued, keep 8 in flight)
  stage256(Ap + 0 * 64, K, &lds[0][0][0], w, lane);
  stage256(Bp + 0 * 64, K, &lds[0][1][0], w, lane);
  stage256(Ap + 1 * 64, K, &lds[1][0][0], w, lane);
  stage256(Bp + 1 * 64, K, &lds[1][1][0], w, lane);
  VM8(); BAR();

  for (int t = 0; t < NT; ++t) {
    const int bufi = t & 1;
    const u16* lA = &lds[bufi][0][0];
    const u16* lB = &lds[bufi][1][0];
    const bool pf = (t + 2 < NT);
    // ---- P0: read A-sub0 + B-sub0 ; MFMA Q(0,0)
    ldAT<0>(af, lA, wr, lr, hi); ldBT<0>(bq, lB, wc, lr, hi);
    BAR(); quadT<0, 0>(acc, af, bq); LGKM0(); BAR();
    // ---- P1: read B-sub1 ; MFMA Q(0,1)
    ldBT<1>(bq, lB, wc, lr, hi);
    BAR(); quadT<0, 1>(acc, af, bq); LGKM0(); BAR();
    // ---- P2: read A-sub1 ; stage B(t+2) into this buf (B reads done @P1) ; Q(1,1)
    ldAT<1>(af, lA, wr, lr, hi);
    if (pf) stage256(Bp + (size_t)(t + 2) * 64, K, &lds[bufi][1][0], w, lane);
    BAR(); quadT<1, 1>(acc, af, bq); LGKM0(); BAR();
    // ---- P3: stage A(t+2) (A reads done @P2) ; Q(1,0) ; counted vmcnt
    if (pf) stage256(Ap + (size_t)(t + 2) * 64, K, &lds[bufi][0][0], w, lane);
    BAR(); quadT<1, 0>(acc, af, bq);
    if (pf) { VM8(); } else if (t + 1 < NT) { VM0(); }
    BAR();
  }

  // epilogue
  const int r0 = tm * 256 + wr * 128;
  const int c0 = tn * 256 + wc * 64;
  float bv[4];
  #pragma unroll
  for (int n = 0; n < 4; ++n) {
    int col = c0 + n * 16 + lr;
    bv[n] = (!NCHK || col < N) ? bias[col] : 0.f;
  }
  #pragma unroll
  for (int m = 0; m < 8; ++m)
    #pragma unroll
    for (int j = 0; j < 4; ++j) {
      int row = r0 + m * 16 + hi * 4 + j;
      #pragma unroll
      for (int n = 0; n < 4; ++n) {
        int col = c0 + n * 16 + lr;
        if (NCHK && col >= N) continue;
        float v = acc[m][n][j] + bv[n];
        if (ACT == 1) v = fmaxf(v, 0.f);
        if (ACT == 2) v = 1.f / (1.f + __expf(-v));
        size_t o = (size_t)row * ldc + col;
        if (OMODE == 0) Cf[o] = v;
        else if (OMODE == 1) Cb[o] = f2bf(v);
        else { Cf[o] = v; Cb[o] = f2bf(v); }
      }
    }
}

// ---------- argmin over codes + gather q + loss partial ----------
__global__ __launch_bounds__(256)
void vq_argmin(const float* __restrict__ zf, const float* __restrict__ scores,
               const float* __restrict__ emb, const float* __restrict__ cvec,
               u16* __restrict__ qb, float* __restrict__ lossacc, int nrows) {
  int wave = threadIdx.x >> 6, lane = threadIdx.x & 63;
  float lsum = 0.f;
  for (int r = blockIdx.x * 4 + wave; r < nrows; r += gridDim.x * 4) {
    const float* srow = scores + (size_t)r * NE;
    float best = 3.4e38f; int bidx = 0;
    #pragma unroll
    for (int i = 0; i < 8; ++i) {
      int j = i * 64 + lane;
      float v = cvec[j] - srow[j];
      if (v < best) { best = v; bidx = j; }
    }
    #pragma unroll
    for (int off = 32; off > 0; off >>= 1) {
      float ov = __shfl_down(best, off);
      int   oi = __shfl_down(bidx, off);
      if (ov < best || (ov == best && oi < bidx)) { best = ov; bidx = oi; }
    }
    bidx = __shfl(bidx, 0);
    float e = emb[bidx * ND + lane];
    float d = e - zf[(size_t)r * ND + lane];
    lsum += d * d;
    qb[(size_t)r * ND + lane] = f2bf(e);
  }
  #pragma unroll
  for (int off = 32; off > 0; off >>= 1) lsum += __shfl_down(lsum, off);
  if (lane == 0) atomicAdd(lossacc, lsum);
}

__global__ void loss_final(const float* __restrict__ acc, float* __restrict__ o, float denom) {
  o[0] = acc[0] * 1.25f / denom;
}

// ---------- launch ----------
extern "C" void kernel_launch(void* const* d_in, const int* in_sizes, int n_in,
                              void* d_out, int out_size, void* d_ws, size_t ws_size,
                              hipStream_t stream) {
  const float* x   = (const float*)d_in[0];
  const float* emb = (const float*)d_in[1];
  const float* We1 = (const float*)d_in[2];
  const float* be1 = (const float*)d_in[3];
  const float* We2 = (const float*)d_in[4];
  const float* be2 = (const float*)d_in[5];
  const float* We3 = (const float*)d_in[6];
  const float* be3 = (const float*)d_in[7];
  const float* Wd1 = (const float*)d_in[8];
  const float* bd1 = (const float*)d_in[9];
  const float* Wd2 = (const float*)d_in[10];
  const float* bd2 = (const float*)d_in[11];
  const float* Wd3 = (const float*)d_in[12];
  const float* bd3 = (const float*)d_in[13];

  const int Bn = in_sizes[0] / NIN;              // 32768
  float* out = (float*)d_out;
  float* out_loss = out + (size_t)Bn * NIN;

  char* ws = (char*)d_ws;
  size_t off = 0;
  auto take = [&](size_t bytes) { char* p = ws + off; off += (bytes + 255) & ~(size_t)255; return p; };

  u16*   xpad = (u16*)take((size_t)Bn * NINP * 2);
  u16*   hA   = (u16*)take((size_t)Bn * NH * 2);   // h1 -> scores(f32) -> h4
  u16*   hB   = (u16*)take((size_t)Bn * NH * 2);   // h2 -> h3
  float* zf   = (float*)take((size_t)Bn * ND * 4);
  u16*   zb   = (u16*)take((size_t)Bn * ND * 2);
  u16*   qb   = (u16*)take((size_t)Bn * ND * 2);
  u16*   we1p = (u16*)take((size_t)NH * NINP * 2);
  u16*   we2b = (u16*)take((size_t)NH * NH * 2);
  u16*   we3p = (u16*)take((size_t)128 * NH * 2);  // 64 rows + 64 zero rows
  u16*   wd1b = (u16*)take((size_t)NH * ND * 2);
  u16*   wd2b = (u16*)take((size_t)NH * NH * 2);
  u16*   wd3p = (u16*)take((size_t)NOUTP * NH * 2);// 784 rows + 240 zero rows
  u16*   embb = (u16*)take((size_t)NE * ND * 2);
  float* cvec = (float*)take(NE * 4);
  float* lossa = (float*)take(4);
  float* scores = (float*)hA;

  hipMemsetAsync(lossa, 0, 4, stream);

  cast_pad4<<<dim3(1, Bn),    256, 0, stream>>>(x,   xpad, Bn,  NIN, NINP);
  cast_pad4<<<dim3(1, NH),    256, 0, stream>>>(We1, we1p, NH,  NIN, NINP);
  cast_pad4<<<dim3(1, NH),    256, 0, stream>>>(We2, we2b, NH,  NH,  NH);
  cast_pad4<<<dim3(1, 128),   256, 0, stream>>>(We3, we3p, ND,  NH,  NH);
  cast_pad4<<<dim3(1, NH),    256, 0, stream>>>(Wd1, wd1b, NH,  ND,  ND);
  cast_pad4<<<dim3(1, NH),    256, 0, stream>>>(Wd2, wd2b, NH,  NH,  NH);
  cast_pad4<<<dim3(1, NOUTP), 256, 0, stream>>>(Wd3, wd3p, NIN, NH,  NH);
  emb_prep<<<NE, 64, 0, stream>>>(emb, embb, cvec);

  const int mt = Bn / 256;                       // 128
  // encoder (8-phase 256^2 for the wide GEMMs)
  gemm256<1,1,false><<<mt * (NH/256), 512, 0, stream>>>(xpad, we1p, be1, nullptr, hA, Bn, NH, NINP, NH, mt);
  gemm256<1,1,false><<<mt * (NH/256), 512, 0, stream>>>(hA, we2b, be2, nullptr, hB, Bn, NH, NH, NH, mt);
  gemm_bt<0,2,true ><<<dim3(Bn/128, 1), 256, 0, stream>>>(hB, we3p, be3, zf, zb, Bn, ND, NH, ND);
  // VQ
  gemm_bt<0,0,false><<<dim3(Bn/128, NE/128), 256, 0, stream>>>(zb, embb, nullptr, scores, nullptr, Bn, NE, ND, NE);
  vq_argmin<<<1024, 256, 0, stream>>>(zf, scores, emb, cvec, qb, lossa, Bn);
  // decoder
  gemm_bt<1,1,false><<<dim3(Bn/128, NH/128), 256, 0, stream>>>(qb, wd1b, bd1, nullptr, hB, Bn, NH, ND, NH);
  gemm256<1,1,false><<<mt * (NH/256), 512, 0, stream>>>(hB, wd2b, bd2, nullptr, (u16*)hA, Bn, NH, NH, NH, mt);
  gemm256<2,0,true ><<<mt * (NOUTP/256), 512, 0, stream>>>((u16*)hA, wd3p, bd3, out, nullptr, Bn, NIN, NH, NIN, mt);

  loss_final<<<1, 1, 0, stream>>>(lossa, out_loss, (float)Bn * ND);
}

// Round 3
// 502.821 us; speedup vs baseline: 1.1802x; 1.0120x over previous
//
#include <hip/hip_runtime.h>
#include <stdint.h>
#include <stddef.h>

typedef __bf16 bf16x8 __attribute__((ext_vector_type(8)));
typedef float  f32x4  __attribute__((ext_vector_type(4)));
typedef unsigned short u16;

#define NIN   784
#define NINP  896    // 784 padded to 14*64
#define NH    1024
#define NE    512
#define ND    64
#define NOUTP 1024   // Wd3 rows padded to 4*256

#define BAR()   asm volatile("s_barrier" ::: "memory")
#define LGKM0() asm volatile("s_waitcnt lgkmcnt(0)" ::: "memory")
#define VM8()   asm volatile("s_waitcnt vmcnt(8)" ::: "memory")
#define VM0()   asm volatile("s_waitcnt vmcnt(0)" ::: "memory")

// Tiled operand layout (both A and B of gemm256):
//   buf[ panel=r>>8 ][ kt=c>>6 ][ r&255 ][ swz chunk ] , 16384 u16 per (panel,kt)
//   element (r,c) -> block (r>>8)*(Cp>>6)+(c>>6), offset (r&255)*64 + (((c>>3)&7)^(r&7))*8 + (c&7)
// The XOR swizzle is baked at write time; staging to LDS is a pure linear copy.

static __device__ __forceinline__ u16 f2bf(float f) {
  union { float f; unsigned u; } v; v.f = f;
  unsigned r = v.u + 0x7fffu + ((v.u >> 16) & 1u);
  return (u16)(r >> 16);
}

static __device__ __forceinline__ size_t tiled_off(int r, int c, int Cp) {
  return ((size_t)(r >> 8) * (Cp >> 6) + (c >> 6)) * 16384
       + ((r & 255) << 6) + (((((c >> 3) & 7) ^ (r & 7))) << 3) + (c & 7);
}

// ---------- cast fp32 -> bf16, row-major (small weights only) ----------
__global__ void cast_rm4(const float* __restrict__ src, u16* __restrict__ dst,
                         int R, int C, int Cp) {
  int r = blockIdx.y;
  int c4 = (blockIdx.x * blockDim.x + threadIdx.x) * 4;
  if (c4 >= Cp) return;
  ushort4 o = {0, 0, 0, 0};
  if (r < R && c4 < C) {
    const float4 v = *(const float4*)&src[(size_t)r * C + c4];
    o.x = f2bf(v.x); o.y = f2bf(v.y); o.z = f2bf(v.z); o.w = f2bf(v.w);
  }
  *(ushort4*)&dst[(size_t)r * Cp + c4] = o;
}

// ---------- cast fp32 -> bf16 into tiled+swizzled layout ----------
__global__ void cast_tiled4(const float* __restrict__ src, u16* __restrict__ dst,
                            int R, int C, int Cp) {
  int r = blockIdx.y;                       // 0..Rp-1 (Rp = gridDim.y, mult of 256)
  int c4 = (blockIdx.x * blockDim.x + threadIdx.x) * 4;
  if (c4 >= Cp) return;
  ushort4 o = {0, 0, 0, 0};
  if (r < R && c4 < C) {
    const float4 v = *(const float4*)&src[(size_t)r * C + c4];
    o.x = f2bf(v.x); o.y = f2bf(v.y); o.z = f2bf(v.z); o.w = f2bf(v.w);
  }
  *(ushort4*)&dst[tiled_off(r, c4, Cp)] = o;  // c4%4==0 -> 4 elems share a chunk
}

// ---------- emb -> bf16 + per-code squared norm ----------
__global__ void emb_prep(const float* __restrict__ emb, u16* __restrict__ ebf,
                         float* __restrict__ cvec) {
  int j = blockIdx.x, l = threadIdx.x;
  float v = emb[j * ND + l];
  ebf[j * ND + l] = f2bf(v);
  float s = v * v;
  #pragma unroll
  for (int off = 32; off > 0; off >>= 1) s += __shfl_down(s, off);
  if (l == 0) cvec[j] = s;
}

// =========================================================================
// 128x128-tile GEMM (m97 structure) — only for K=64 GEMMs (VQ scores, D1).
// A,B row-major [*][64]: a 128-row tile is already 16 KB contiguous.
// =========================================================================
__device__ __forceinline__ void stage_tile(const u16* __restrict__ src,
                                           int ld, u16* lds, int t) {
  int wave = t >> 6;
  #pragma unroll
  for (int i = 0; i < 4; ++i) {
    int c = i * 256 + t;
    int row = c >> 3;
    int col = (c & 7) << 3;
    const u16* g = src + (size_t)row * ld + col;
    u16* l = lds + (size_t)(i * 256 + wave * 64) * 8;
    __builtin_amdgcn_global_load_lds((__attribute__((address_space(1))) void*)g,
                                     (__attribute__((address_space(3))) void*)l,
                                     16, 0, 0);
  }
}

template <int ACT, int OMODE>   // OMODE: 0 = f32 row-major, 3 = bf16 tiled-swz
__global__ __launch_bounds__(256, 2)
void gemm_bt(const u16* __restrict__ A, const u16* __restrict__ Bm,
             const float* __restrict__ bias, float* __restrict__ Cf,
             u16* __restrict__ Cb, int M, int N, int K, int ldc) {
  __shared__ u16 lsA[128 * 64];
  __shared__ u16 lsB[128 * 64];
  const int t = threadIdx.x;
  const int lane = t & 63;
  const int wave = t >> 6;
  const int wr = wave >> 1, wc = wave & 1;
  const int tm = blockIdx.x, tn = blockIdx.y;

  const u16* Ap = A + (size_t)tm * 128 * K;
  const u16* Bp = Bm + (size_t)tn * 128 * K;

  f32x4 acc[4][4] = {};
  const int lr = lane & 15;
  const int lk = (lane >> 4) << 3;

  for (int k0 = 0; k0 < K; k0 += 64) {
    stage_tile(Ap + k0, K, lsA, t);
    stage_tile(Bp + k0, K, lsB, t);
    __syncthreads();
    #pragma unroll
    for (int kk = 0; kk < 64; kk += 32) {
      bf16x8 af[4], bfr[4];
      #pragma unroll
      for (int m = 0; m < 4; ++m)
        af[m] = *(const bf16x8*)&lsA[(wr * 64 + m * 16 + lr) * 64 + kk + lk];
      #pragma unroll
      for (int n = 0; n < 4; ++n)
        bfr[n] = *(const bf16x8*)&lsB[(wc * 64 + n * 16 + lr) * 64 + kk + lk];
      #pragma unroll
      for (int m = 0; m < 4; ++m)
        #pragma unroll
        for (int n = 0; n < 4; ++n)
          acc[m][n] = __builtin_amdgcn_mfma_f32_16x16x32_bf16(af[m], bfr[n], acc[m][n], 0, 0, 0);
    }
    __syncthreads();
  }

  const int r0 = tm * 128 + wr * 64;
  const int c0 = tn * 128 + wc * 64;
  const int rsub = (lane >> 4) * 4;
  float bv[4];
  #pragma unroll
  for (int n = 0; n < 4; ++n) bv[n] = bias ? bias[c0 + n * 16 + lr] : 0.f;
  #pragma unroll
  for (int m = 0; m < 4; ++m)
    #pragma unroll
    for (int j = 0; j < 4; ++j) {
      int row = r0 + m * 16 + rsub + j;
      #pragma unroll
      for (int n = 0; n < 4; ++n) {
        int col = c0 + n * 16 + lr;
        float v = acc[m][n][j] + bv[n];
        if (ACT == 1) v = fmaxf(v, 0.f);
        if (OMODE == 0) Cf[(size_t)row * ldc + col] = v;
        else            Cb[tiled_off(row, col, N)] = f2bf(v);
      }
    }
}

// =========================================================================
// 256x256-tile, BK=64, 8-wave, 8-phase GEMM. Operands in tiled-swz layout;
// staging is a pure linear 32 KB copy per (matrix, K-tile).
// =========================================================================
__device__ __forceinline__ void stageL(const u16* __restrict__ src,
                                       u16* dstmat, int w, int lane) {
  #pragma unroll
  for (int i = 0; i < 4; ++i) {
    const u16* g = src + (size_t)((i * 512 + w * 64 + lane) << 3);
    u16* l = dstmat + (size_t)((i * 512 + w * 64) << 3);   // + lane*16B by HW
    __builtin_amdgcn_global_load_lds((__attribute__((address_space(1))) void*)g,
                                     (__attribute__((address_space(3))) void*)l,
                                     16, 0, 0);
  }
}

template <int S>
__device__ __forceinline__ void ldAT(bf16x8 (&af)[4][2], const u16* mat,
                                     int wr, int lr, int hi) {
  #pragma unroll
  for (int m = 0; m < 4; ++m)
    #pragma unroll
    for (int e = 0; e < 2; ++e) {
      int row = wr * 128 + S * 64 + m * 16 + lr;
      int c = (e * 4 + hi) ^ (lr & 7);
      af[m][e] = *(const bf16x8*)&mat[row * 64 + c * 8];
    }
}

template <int S>
__device__ __forceinline__ void ldBT(bf16x8 (&bq)[2][2][2], const u16* mat,
                                     int wc, int lr, int hi) {
  #pragma unroll
  for (int f = 0; f < 2; ++f)
    #pragma unroll
    for (int e = 0; e < 2; ++e) {
      int row = wc * 64 + S * 32 + f * 16 + lr;
      int c = (e * 4 + hi) ^ (lr & 7);
      bq[S][f][e] = *(const bf16x8*)&mat[row * 64 + c * 8];
    }
}

template <int MS, int NS>
__device__ __forceinline__ void quadT(f32x4 (&acc)[8][4], bf16x8 (&af)[4][2],
                                      bf16x8 (&bq)[2][2][2]) {
  __builtin_amdgcn_s_setprio(1);
  #pragma unroll
  for (int m = 0; m < 4; ++m)
    #pragma unroll
    for (int f = 0; f < 2; ++f)
      #pragma unroll
      for (int e = 0; e < 2; ++e)
        acc[MS * 4 + m][NS * 2 + f] = __builtin_amdgcn_mfma_f32_16x16x32_bf16(
            af[m][e], bq[NS][f][e], acc[MS * 4 + m][NS * 2 + f], 0, 0, 0);
  __builtin_amdgcn_s_setprio(0);
}

template <int ACT, int OMODE, bool NCHK>  // OMODE: 0 f32 rm, 1 bf16 tiled, 2 f32 rm + bf16 rm
__global__ __launch_bounds__(512, 2)
void gemm256(const u16* __restrict__ A, const u16* __restrict__ Bm,
             const float* __restrict__ bias, float* __restrict__ Cf,
             u16* __restrict__ Cb, int M, int N, int K, int ldc, int ntiles) {
  __shared__ __attribute__((aligned(128))) u16 lds[2][2][256 * 64];  // 128 KiB
  const int tid  = threadIdx.x;
  const int lane = tid & 63;
  const int w    = tid >> 6;
  const int wr   = w >> 2, wc = w & 3;       // 2x4 waves, 128x64 out each
  const int lr   = lane & 15, hi = lane >> 4;

  // chunked XCD swizzle (nwg % 8 == 0); tn fast -> A-panel sharers on same XCD
  int nwg = gridDim.x, cpx = nwg >> 3, b = blockIdx.x;
  int sb = (b & 7) * cpx + (b >> 3);
  int tm = sb / ntiles, tn = sb % ntiles;

  const int NTk = K >> 6;
  const u16* Ap = A + (size_t)tm * NTk * 16384;
  const u16* Bp = Bm + (size_t)tn * NTk * 16384;

  f32x4 acc[8][4] = {};
  bf16x8 af[4][2], bq[2][2][2];

  stageL(Ap + 0 * 16384, &lds[0][0][0], w, lane);
  stageL(Bp + 0 * 16384, &lds[0][1][0], w, lane);
  stageL(Ap + 1 * 16384, &lds[1][0][0], w, lane);
  stageL(Bp + 1 * 16384, &lds[1][1][0], w, lane);
  VM8(); BAR();

  for (int t = 0; t < NTk; ++t) {
    const int bufi = t & 1;
    const u16* lA = &lds[bufi][0][0];
    const u16* lB = &lds[bufi][1][0];
    const bool pf = (t + 2 < NTk);
    // P0: read A-sub0 + B-sub0 ; Q(0,0)
    ldAT<0>(af, lA, wr, lr, hi); ldBT<0>(bq, lB, wc, lr, hi);
    BAR(); quadT<0, 0>(acc, af, bq); LGKM0(); BAR();
    // P1: read B-sub1 ; Q(0,1)
    ldBT<1>(bq, lB, wc, lr, hi);
    BAR(); quadT<0, 1>(acc, af, bq); LGKM0(); BAR();
    // P2: read A-sub1 ; stage B(t+2) ; Q(1,1)
    ldAT<1>(af, lA, wr, lr, hi);
    if (pf) stageL(Bp + (size_t)(t + 2) * 16384, &lds[bufi][1][0], w, lane);
    BAR(); quadT<1, 1>(acc, af, bq); LGKM0(); BAR();
    // P3: stage A(t+2) ; Q(1,0) ; counted vmcnt
    if (pf) stageL(Ap + (size_t)(t + 2) * 16384, &lds[bufi][0][0], w, lane);
    BAR(); quadT<1, 0>(acc, af, bq);
    if (pf) { VM8(); } else if (t + 1 < NTk) { VM0(); }
    BAR();
  }

  const int r0 = tm * 256 + wr * 128;
  const int c0 = tn * 256 + wc * 64;
  float bv[4];
  #pragma unroll
  for (int n = 0; n < 4; ++n) {
    int col = c0 + n * 16 + lr;
    bv[n] = (!NCHK || col < N) ? bias[col] : 0.f;
  }
  #pragma unroll
  for (int m = 0; m < 8; ++m)
    #pragma unroll
    for (int j = 0; j < 4; ++j) {
      int row = r0 + m * 16 + hi * 4 + j;
      if (OMODE == 1) {
        // dense 16 KB per-wave window in consumer's tiled layout
        size_t rb = ((size_t)(row >> 8) * (N >> 6) + (c0 >> 6)) * 16384 + ((row & 255) << 6);
        #pragma unroll
        for (int n = 0; n < 4; ++n) {
          int col = c0 + n * 16 + lr;
          float v = acc[m][n][j] + bv[n];
          if (ACT == 1) v = fmaxf(v, 0.f);
          int w64 = col & 63;
          Cb[rb + ((((w64 >> 3) ^ (row & 7))) << 3) + (w64 & 7)] = f2bf(v);
        }
      } else {
        #pragma unroll
        for (int n = 0; n < 4; ++n) {
          int col = c0 + n * 16 + lr;
          if (NCHK && col >= N) continue;
          float v = acc[m][n][j] + bv[n];
          if (ACT == 1) v = fmaxf(v, 0.f);
          if (ACT == 2) v = 1.f / (1.f + __expf(-v));
          size_t o = (size_t)row * ldc + col;
          if (OMODE == 0) Cf[o] = v;
          else { Cf[o] = v; Cb[o] = f2bf(v); }
        }
      }
    }
}

// ---------- argmin over codes + gather q + loss partial ----------
__global__ __launch_bounds__(256)
void vq_argmin(const float* __restrict__ zf, const float* __restrict__ scores,
               const float* __restrict__ emb, const float* __restrict__ cvec,
               u16* __restrict__ qb, float* __restrict__ lossacc, int nrows) {
  int wave = threadIdx.x >> 6, lane = threadIdx.x & 63;
  float lsum = 0.f;
  for (int r = blockIdx.x * 4 + wave; r < nrows; r += gridDim.x * 4) {
    const float* srow = scores + (size_t)r * NE;
    float best = 3.4e38f; int bidx = 0;
    #pragma unroll
    for (int i = 0; i < 8; ++i) {
      int j = i * 64 + lane;
      float v = cvec[j] - srow[j];
      if (v < best) { best = v; bidx = j; }
    }
    #pragma unroll
    for (int off = 32; off > 0; off >>= 1) {
      float ov = __shfl_down(best, off);
      int   oi = __shfl_down(bidx, off);
      if (ov < best || (ov == best && oi < bidx)) { best = ov; bidx = oi; }
    }
    bidx = __shfl(bidx, 0);
    float e = emb[bidx * ND + lane];
    float d = e - zf[(size_t)r * ND + lane];
    lsum += d * d;
    qb[(size_t)r * ND + lane] = f2bf(e);
  }
  #pragma unroll
  for (int off = 32; off > 0; off >>= 1) lsum += __shfl_down(lsum, off);
  if (lane == 0) atomicAdd(lossacc, lsum);
}

__global__ void loss_final(const float* __restrict__ acc, float* __restrict__ o, float denom) {
  o[0] = acc[0] * 1.25f / denom;
}

// ---------- launch ----------
extern "C" void kernel_launch(void* const* d_in, const int* in_sizes, int n_in,
                              void* d_out, int out_size, void* d_ws, size_t ws_size,
                              hipStream_t stream) {
  const float* x   = (const float*)d_in[0];
  const float* emb = (const float*)d_in[1];
  const float* We1 = (const float*)d_in[2];
  const float* be1 = (const float*)d_in[3];
  const float* We2 = (const float*)d_in[4];
  const float* be2 = (const float*)d_in[5];
  const float* We3 = (const float*)d_in[6];
  const float* be3 = (const float*)d_in[7];
  const float* Wd1 = (const float*)d_in[8];
  const float* bd1 = (const float*)d_in[9];
  const float* Wd2 = (const float*)d_in[10];
  const float* bd2 = (const float*)d_in[11];
  const float* Wd3 = (const float*)d_in[12];
  const float* bd3 = (const float*)d_in[13];

  const int Bn = in_sizes[0] / NIN;              // 32768
  float* out = (float*)d_out;
  float* out_loss = out + (size_t)Bn * NIN;

  char* ws = (char*)d_ws;
  size_t off = 0;
  auto take = [&](size_t bytes) { char* p = ws + off; off += (bytes + 255) & ~(size_t)255; return p; };

  u16*   xpad = (u16*)take((size_t)Bn * NINP * 2);   // tiled
  u16*   hA   = (u16*)take((size_t)Bn * NH * 2);     // tiled: h1 -> scores(f32 rm) -> h3
  u16*   hB   = (u16*)take((size_t)Bn * NH * 2);     // tiled: h2 -> h4
  float* zf   = (float*)take((size_t)Bn * ND * 4);
  u16*   zb   = (u16*)take((size_t)Bn * ND * 2);     // row-major == tiled at 64 wide
  u16*   qb   = (u16*)take((size_t)Bn * ND * 2);
  u16*   we1p = (u16*)take((size_t)NH * NINP * 2);   // tiled
  u16*   we2b = (u16*)take((size_t)NH * NH * 2);     // tiled
  u16*   we3p = (u16*)take((size_t)256 * NH * 2);    // tiled, rows 64..255 zero
  u16*   wd1b = (u16*)take((size_t)NH * ND * 2);     // row-major (K=64)
  u16*   wd2b = (u16*)take((size_t)NH * NH * 2);     // tiled
  u16*   wd3p = (u16*)take((size_t)NOUTP * NH * 2);  // tiled, rows 784..1023 zero
  u16*   embb = (u16*)take((size_t)NE * ND * 2);     // row-major (K=64)
  float* cvec = (float*)take(NE * 4);
  float* lossa = (float*)take(4);
  float* scores = (float*)hA;                        // dead interval of hA

  hipMemsetAsync(lossa, 0, 4, stream);

  cast_tiled4<<<dim3(1, Bn),    256, 0, stream>>>(x,   xpad, Bn,  NIN, NINP);
  cast_tiled4<<<dim3(1, NH),    256, 0, stream>>>(We1, we1p, NH,  NIN, NINP);
  cast_tiled4<<<dim3(1, NH),    256, 0, stream>>>(We2, we2b, NH,  NH,  NH);
  cast_tiled4<<<dim3(1, 256),   256, 0, stream>>>(We3, we3p, ND,  NH,  NH);
  cast_rm4  <<<dim3(1, NH),     256, 0, stream>>>(Wd1, wd1b, NH,  ND,  ND);
  cast_tiled4<<<dim3(1, NH),    256, 0, stream>>>(Wd2, wd2b, NH,  NH,  NH);
  cast_tiled4<<<dim3(1, NOUTP), 256, 0, stream>>>(Wd3, wd3p, NIN, NH,  NH);
  emb_prep<<<NE, 64, 0, stream>>>(emb, embb, cvec);

  // encoder
  gemm256<1,1,false><<<512, 512, 0, stream>>>(xpad, we1p, be1, nullptr, hA, Bn, NH, NINP, NH, 4);
  gemm256<1,1,false><<<512, 512, 0, stream>>>(hA, we2b, be2, nullptr, hB, Bn, NH, NH, NH, 4);
  gemm256<0,2,true ><<<128, 512, 0, stream>>>(hB, we3p, be3, zf, zb, Bn, ND, NH, ND, 1);
  // VQ
  gemm_bt<0,0><<<dim3(Bn/128, NE/128), 256, 0, stream>>>(zb, embb, nullptr, scores, nullptr, Bn, NE, ND, NE);
  vq_argmin<<<1024, 256, 0, stream>>>(zf, scores, emb, cvec, qb, lossa, Bn);
  // decoder
  gemm_bt<1,3><<<dim3(Bn/128, NH/128), 256, 0, stream>>>(qb, wd1b, bd1, nullptr, hA, Bn, NH, ND, NH);
  gemm256<1,1,false><<<512, 512, 0, stream>>>(hA, wd2b, bd2, nullptr, hB, Bn, NH, NH, NH, 4);
  gemm256<2,0,true ><<<512, 512, 0, stream>>>(hB, wd3p, bd3, out, nullptr, Bn, NIN, NH, NIN, 4);

  loss_final<<<1, 1, 0, stream>>>(lossa, out_loss, (float)Bn * ND);
}

// Round 4
// 496.322 us; speedup vs baseline: 1.1957x; 1.0131x over previous
//
#include <hip/hip_runtime.h>
#include <stdint.h>
#include <stddef.h>

typedef __bf16 bf16x8 __attribute__((ext_vector_type(8)));
typedef float  f32x4  __attribute__((ext_vector_type(4)));
typedef unsigned short u16;

#define NIN   784
#define NINP  896    // 784 padded to 14*64
#define NH    1024
#define NE    512
#define ND    64
#define NOUTP 1024   // Wd3 rows padded to 4*256

#define SBAR()   __builtin_amdgcn_s_barrier()
#define SCHED0() __builtin_amdgcn_sched_barrier(0)
#define LGKM0()  asm volatile("s_waitcnt lgkmcnt(0)" ::: "memory")
#define VM8()    asm volatile("s_waitcnt vmcnt(8)" ::: "memory")
#define VM0()    asm volatile("s_waitcnt vmcnt(0)" ::: "memory")

// Tiled operand layout (A and B of gemm256):
//   element (r,c) -> block (r>>8)*(Cp>>6)+(c>>6), offset (r&255)*64 + ((((c>>3)&7)^(r&7))<<3) + (c&7)
// XOR swizzle baked at write time; LDS staging is a pure linear copy.

static __device__ __forceinline__ u16 f2bf(float f) {
  union { float f; unsigned u; } v; v.f = f;
  unsigned r = v.u + 0x7fffu + ((v.u >> 16) & 1u);
  return (u16)(r >> 16);
}

static __device__ __forceinline__ size_t tiled_off(int r, int c, int Cp) {
  return ((size_t)(r >> 8) * (Cp >> 6) + (c >> 6)) * 16384
       + ((r & 255) << 6) + (((((c >> 3) & 7) ^ (r & 7))) << 3) + (c & 7);
}

// ---------- cast fp32 -> bf16, row-major ----------
__global__ void cast_rm4(const float* __restrict__ src, u16* __restrict__ dst,
                         int R, int C, int Cp) {
  int r = blockIdx.y;
  int c4 = (blockIdx.x * blockDim.x + threadIdx.x) * 4;
  if (c4 >= Cp) return;
  ushort4 o = {0, 0, 0, 0};
  if (r < R && c4 < C) {
    const float4 v = *(const float4*)&src[(size_t)r * C + c4];
    o.x = f2bf(v.x); o.y = f2bf(v.y); o.z = f2bf(v.z); o.w = f2bf(v.w);
  }
  *(ushort4*)&dst[(size_t)r * Cp + c4] = o;
}

// ---------- cast fp32 -> bf16 into tiled+swizzled layout ----------
__global__ void cast_tiled4(const float* __restrict__ src, u16* __restrict__ dst,
                            int R, int C, int Cp) {
  int r = blockIdx.y;
  int c4 = (blockIdx.x * blockDim.x + threadIdx.x) * 4;
  if (c4 >= Cp) return;
  ushort4 o = {0, 0, 0, 0};
  if (r < R && c4 < C) {
    const float4 v = *(const float4*)&src[(size_t)r * C + c4];
    o.x = f2bf(v.x); o.y = f2bf(v.y); o.z = f2bf(v.z); o.w = f2bf(v.w);
  }
  *(ushort4*)&dst[tiled_off(r, c4, Cp)] = o;
}

// ---------- emb -> bf16 + per-code squared norm ----------
__global__ void emb_prep(const float* __restrict__ emb, u16* __restrict__ ebf,
                         float* __restrict__ cvec) {
  int j = blockIdx.x, l = threadIdx.x;
  float v = emb[j * ND + l];
  ebf[j * ND + l] = f2bf(v);
  float s = v * v;
  #pragma unroll
  for (int off = 32; off > 0; off >>= 1) s += __shfl_down(s, off);
  if (l == 0) cvec[j] = s;
}

// =========================================================================
// 128x128-tile GEMM (m97 structure) — K=64 GEMMs only (VQ scores, D1).
// =========================================================================
__device__ __forceinline__ void stage_tile(const u16* __restrict__ src,
                                           int ld, u16* lds, int t) {
  int wave = t >> 6;
  #pragma unroll
  for (int i = 0; i < 4; ++i) {
    int c = i * 256 + t;
    int row = c >> 3;
    int col = (c & 7) << 3;
    const u16* g = src + (size_t)row * ld + col;
    u16* l = lds + (size_t)(i * 256 + wave * 64) * 8;
    __builtin_amdgcn_global_load_lds((__attribute__((address_space(1))) void*)g,
                                     (__attribute__((address_space(3))) void*)l,
                                     16, 0, 0);
  }
}

template <int ACT, int OMODE>   // OMODE: 0 = f32 row-major, 3 = bf16 tiled-swz
__global__ __launch_bounds__(256, 2)
void gemm_bt(const u16* __restrict__ A, const u16* __restrict__ Bm,
             const float* __restrict__ bias, float* __restrict__ Cf,
             u16* __restrict__ Cb, int M, int N, int K, int ldc) {
  __shared__ u16 lsA[128 * 64];
  __shared__ u16 lsB[128 * 64];
  const int t = threadIdx.x;
  const int lane = t & 63;
  const int wave = t >> 6;
  const int wr = wave >> 1, wc = wave & 1;
  const int tm = blockIdx.x, tn = blockIdx.y;

  const u16* Ap = A + (size_t)tm * 128 * K;
  const u16* Bp = Bm + (size_t)tn * 128 * K;

  f32x4 acc[4][4] = {};
  const int lr = lane & 15;
  const int lk = (lane >> 4) << 3;

  for (int k0 = 0; k0 < K; k0 += 64) {
    stage_tile(Ap + k0, K, lsA, t);
    stage_tile(Bp + k0, K, lsB, t);
    __syncthreads();
    #pragma unroll
    for (int kk = 0; kk < 64; kk += 32) {
      bf16x8 af[4], bfr[4];
      #pragma unroll
      for (int m = 0; m < 4; ++m)
        af[m] = *(const bf16x8*)&lsA[(wr * 64 + m * 16 + lr) * 64 + kk + lk];
      #pragma unroll
      for (int n = 0; n < 4; ++n)
        bfr[n] = *(const bf16x8*)&lsB[(wc * 64 + n * 16 + lr) * 64 + kk + lk];
      #pragma unroll
      for (int m = 0; m < 4; ++m)
        #pragma unroll
        for (int n = 0; n < 4; ++n)
          acc[m][n] = __builtin_amdgcn_mfma_f32_16x16x32_bf16(af[m], bfr[n], acc[m][n], 0, 0, 0);
    }
    __syncthreads();
  }

  const int r0 = tm * 128 + wr * 64;
  const int c0 = tn * 128 + wc * 64;
  const int rsub = (lane >> 4) * 4;
  float bv[4];
  #pragma unroll
  for (int n = 0; n < 4; ++n) bv[n] = bias ? bias[c0 + n * 16 + lr] : 0.f;
  #pragma unroll
  for (int m = 0; m < 4; ++m)
    #pragma unroll
    for (int j = 0; j < 4; ++j) {
      int row = r0 + m * 16 + rsub + j;
      #pragma unroll
      for (int n = 0; n < 4; ++n) {
        int col = c0 + n * 16 + lr;
        float v = acc[m][n][j] + bv[n];
        if (ACT == 1) v = fmaxf(v, 0.f);
        if (OMODE == 0) Cf[(size_t)row * ldc + col] = v;
        else            Cb[tiled_off(row, col, N)] = f2bf(v);
      }
    }
}

// =========================================================================
// 256x256-tile, BK=64, 8-wave, 8-phase GEMM with sched_barrier-pinned phases.
// =========================================================================
__device__ __forceinline__ void stageL(const u16* __restrict__ src,
                                       u16* dstmat, int w, int lane) {
  #pragma unroll
  for (int i = 0; i < 4; ++i) {
    const u16* g = src + (size_t)((i * 512 + w * 64 + lane) << 3);
    u16* l = dstmat + (size_t)((i * 512 + w * 64) << 3);   // + lane*16B by HW
    __builtin_amdgcn_global_load_lds((__attribute__((address_space(1))) void*)g,
                                     (__attribute__((address_space(3))) void*)l,
                                     16, 0, 0);
  }
}

template <int S>
__device__ __forceinline__ void ldAT(bf16x8 (&af)[4][2], const u16* mat,
                                     int wr, int lr, int hi) {
  #pragma unroll
  for (int m = 0; m < 4; ++m)
    #pragma unroll
    for (int e = 0; e < 2; ++e) {
      int row = wr * 128 + S * 64 + m * 16 + lr;
      int c = (e * 4 + hi) ^ (lr & 7);
      af[m][e] = *(const bf16x8*)&mat[row * 64 + c * 8];
    }
}

template <int S>
__device__ __forceinline__ void ldBT(bf16x8 (&bq)[2][2][2], const u16* mat,
                                     int wc, int lr, int hi) {
  #pragma unroll
  for (int f = 0; f < 2; ++f)
    #pragma unroll
    for (int e = 0; e < 2; ++e) {
      int row = wc * 64 + S * 32 + f * 16 + lr;
      int c = (e * 4 + hi) ^ (lr & 7);
      bq[S][f][e] = *(const bf16x8*)&mat[row * 64 + c * 8];
    }
}

template <int MS, int NS>
__device__ __forceinline__ void quadT(f32x4 (&acc)[8][4], bf16x8 (&af)[4][2],
                                      bf16x8 (&bq)[2][2][2]) {
  __builtin_amdgcn_s_setprio(1);
  #pragma unroll
  for (int m = 0; m < 4; ++m)
    #pragma unroll
    for (int f = 0; f < 2; ++f)
      #pragma unroll
      for (int e = 0; e < 2; ++e)
        acc[MS * 4 + m][NS * 2 + f] = __builtin_amdgcn_mfma_f32_16x16x32_bf16(
            af[m][e], bq[NS][f][e], acc[MS * 4 + m][NS * 2 + f], 0, 0, 0);
  __builtin_amdgcn_s_setprio(0);
}

// One K-tile = 4 pinned phases. STG: issue t+2 stages.  VW: 8=vm8, 0=vm0, -1=none
template <int STG, int VW>
__device__ __forceinline__ void ktile(f32x4 (&acc)[8][4], bf16x8 (&af)[4][2],
                                      bf16x8 (&bq)[2][2][2],
                                      const u16* lA, const u16* lB,
                                      const u16* stA, const u16* stB,
                                      u16* sdA, u16* sdB,
                                      int w, int lane, int wr, int wc, int lr, int hi) {
  // P0: read A-sub0 + B-sub0 ; Q(0,0)
  ldAT<0>(af, lA, wr, lr, hi); ldBT<0>(bq, lB, wc, lr, hi);
  SCHED0(); SBAR(); LGKM0(); SCHED0();
  quadT<0, 0>(acc, af, bq);
  SCHED0(); SBAR();
  // P1: read B-sub1 ; Q(0,1)
  ldBT<1>(bq, lB, wc, lr, hi);
  SCHED0(); SBAR(); LGKM0(); SCHED0();
  quadT<0, 1>(acc, af, bq);
  SCHED0(); SBAR();
  // P2: read A-sub1 ; stage B(t+2) (B reads of this tile finished @P1) ; Q(1,1)
  ldAT<1>(af, lA, wr, lr, hi);
  if (STG) stageL(stB, sdB, w, lane);
  SCHED0(); SBAR(); LGKM0(); SCHED0();
  quadT<1, 1>(acc, af, bq);
  SCHED0(); SBAR();
  // P3: stage A(t+2) (A reads finished @P2) ; Q(1,0) ; counted vmcnt gate
  if (STG) stageL(stA, sdA, w, lane);
  SCHED0(); SBAR();
  quadT<1, 0>(acc, af, bq);
  SCHED0();
  if (VW == 8) { VM8(); } else if (VW == 0) { VM0(); }
  SCHED0(); SBAR();
}

template <int ACT, int OMODE, bool NCHK>  // OMODE: 0 f32 rm, 1 bf16 tiled, 2 f32 rm + bf16 rm
__global__ __launch_bounds__(512, 2)
void gemm256(const u16* __restrict__ A, const u16* __restrict__ Bm,
             const float* __restrict__ bias, float* __restrict__ Cf,
             u16* __restrict__ Cb, int M, int N, int K, int ldc, int ntiles) {
  __shared__ __attribute__((aligned(128))) u16 lds[2][2][256 * 64];  // 128 KiB
  const int tid  = threadIdx.x;
  const int lane = tid & 63;
  const int w    = tid >> 6;
  const int wr   = w >> 2, wc = w & 3;       // 2x4 waves, 128x64 out each
  const int lr   = lane & 15, hi = lane >> 4;

  int nwg = gridDim.x, cpx = nwg >> 3, b = blockIdx.x;
  int sb = (b & 7) * cpx + (b >> 3);
  int tm = sb / ntiles, tn = sb % ntiles;

  const int NT = K >> 6;
  const u16* Ap = A + (size_t)tm * NT * 16384;
  const u16* Bp = Bm + (size_t)tn * NT * 16384;

  f32x4 acc[8][4] = {};
  bf16x8 af[4][2], bq[2][2][2];

  stageL(Ap + 0 * 16384, &lds[0][0][0], w, lane);
  stageL(Bp + 0 * 16384, &lds[0][1][0], w, lane);
  stageL(Ap + 1 * 16384, &lds[1][0][0], w, lane);
  stageL(Bp + 1 * 16384, &lds[1][1][0], w, lane);
  VM8(); SCHED0(); SBAR();

  // hot loop: branch-free, stages unconditional
  for (int t = 0; t < NT - 2; ++t) {
    const int bufi = t & 1;
    ktile<1, 8>(acc, af, bq, &lds[bufi][0][0], &lds[bufi][1][0],
                Ap + (size_t)(t + 2) * 16384, Bp + (size_t)(t + 2) * 16384,
                &lds[bufi][0][0], &lds[bufi][1][0], w, lane, wr, wc, lr, hi);
  }
  {  // t = NT-2: no stage; drain all so tile NT-1 is readable
    const int bufi = (NT - 2) & 1;
    ktile<0, 0>(acc, af, bq, &lds[bufi][0][0], &lds[bufi][1][0],
                nullptr, nullptr, nullptr, nullptr, w, lane, wr, wc, lr, hi);
  }
  {  // t = NT-1: no stage, no vm gate
    const int bufi = (NT - 1) & 1;
    ktile<0, -1>(acc, af, bq, &lds[bufi][0][0], &lds[bufi][1][0],
                 nullptr, nullptr, nullptr, nullptr, w, lane, wr, wc, lr, hi);
  }

  const int r0 = tm * 256 + wr * 128;
  const int c0 = tn * 256 + wc * 64;
  float bv[4];
  #pragma unroll
  for (int n = 0; n < 4; ++n) {
    int col = c0 + n * 16 + lr;
    bv[n] = (!NCHK || col < N) ? bias[col] : 0.f;
  }
  #pragma unroll
  for (int m = 0; m < 8; ++m)
    #pragma unroll
    for (int j = 0; j < 4; ++j) {
      int row = r0 + m * 16 + hi * 4 + j;
      if (OMODE == 1) {
        size_t rb = ((size_t)(row >> 8) * (N >> 6) + (c0 >> 6)) * 16384 + ((row & 255) << 6);
        #pragma unroll
        for (int n = 0; n < 4; ++n) {
          int col = c0 + n * 16 + lr;
          float v = acc[m][n][j] + bv[n];
          if (ACT == 1) v = fmaxf(v, 0.f);
          int w64 = col & 63;
          Cb[rb + ((((w64 >> 3) ^ (row & 7))) << 3) + (w64 & 7)] = f2bf(v);
        }
      } else {
        #pragma unroll
        for (int n = 0; n < 4; ++n) {
          int col = c0 + n * 16 + lr;
          if (NCHK && col >= N) continue;
          float v = acc[m][n][j] + bv[n];
          if (ACT == 1) v = fmaxf(v, 0.f);
          if (ACT == 2) v = 1.f / (1.f + __expf(-v));
          size_t o = (size_t)row * ldc + col;
          if (OMODE == 0) Cf[o] = v;
          else { Cf[o] = v; Cb[o] = f2bf(v); }
        }
      }
    }
}

// ---------- argmin over codes + gather q + loss partial ----------
__global__ __launch_bounds__(256)
void vq_argmin(const float* __restrict__ zf, const float* __restrict__ scores,
               const float* __restrict__ emb, const float* __restrict__ cvec,
               u16* __restrict__ qb, float* __restrict__ lossacc, int nrows) {
  int wave = threadIdx.x >> 6, lane = threadIdx.x & 63;
  float lsum = 0.f;
  for (int r = blockIdx.x * 4 + wave; r < nrows; r += gridDim.x * 4) {
    const float* srow = scores + (size_t)r * NE;
    float best = 3.4e38f; int bidx = 0;
    #pragma unroll
    for (int i = 0; i < 8; ++i) {
      int j = i * 64 + lane;
      float v = cvec[j] - srow[j];
      if (v < best) { best = v; bidx = j; }
    }
    #pragma unroll
    for (int off = 32; off > 0; off >>= 1) {
      float ov = __shfl_down(best, off);
      int   oi = __shfl_down(bidx, off);
      if (ov < best || (ov == best && oi < bidx)) { best = ov; bidx = oi; }
    }
    bidx = __shfl(bidx, 0);
    float e = emb[bidx * ND + lane];
    float d = e - zf[(size_t)r * ND + lane];
    lsum += d * d;
    qb[(size_t)r * ND + lane] = f2bf(e);
  }
  #pragma unroll
  for (int off = 32; off > 0; off >>= 1) lsum += __shfl_down(lsum, off);
  if (lane == 0) atomicAdd(lossacc, lsum);
}

__global__ void loss_final(const float* __restrict__ acc, float* __restrict__ o, float denom) {
  o[0] = acc[0] * 1.25f / denom;
}

// ---------- launch ----------
extern "C" void kernel_launch(void* const* d_in, const int* in_sizes, int n_in,
                              void* d_out, int out_size, void* d_ws, size_t ws_size,
                              hipStream_t stream) {
  const float* x   = (const float*)d_in[0];
  const float* emb = (const float*)d_in[1];
  const float* We1 = (const float*)d_in[2];
  const float* be1 = (const float*)d_in[3];
  const float* We2 = (const float*)d_in[4];
  const float* be2 = (const float*)d_in[5];
  const float* We3 = (const float*)d_in[6];
  const float* be3 = (const float*)d_in[7];
  const float* Wd1 = (const float*)d_in[8];
  const float* bd1 = (const float*)d_in[9];
  const float* Wd2 = (const float*)d_in[10];
  const float* bd2 = (const float*)d_in[11];
  const float* Wd3 = (const float*)d_in[12];
  const float* bd3 = (const float*)d_in[13];

  const int Bn = in_sizes[0] / NIN;              // 32768
  float* out = (float*)d_out;
  float* out_loss = out + (size_t)Bn * NIN;

  char* ws = (char*)d_ws;
  size_t off = 0;
  auto take = [&](size_t bytes) { char* p = ws + off; off += (bytes + 255) & ~(size_t)255; return p; };

  u16*   xpad = (u16*)take((size_t)Bn * NINP * 2);   // tiled
  u16*   hA   = (u16*)take((size_t)Bn * NH * 2);     // tiled: h1 -> scores(f32 rm) -> h3
  u16*   hB   = (u16*)take((size_t)Bn * NH * 2);     // tiled: h2 -> h4
  float* zf   = (float*)take((size_t)Bn * ND * 4);
  u16*   zb   = (u16*)take((size_t)Bn * ND * 2);     // row-major == tiled at 64 wide
  u16*   qb   = (u16*)take((size_t)Bn * ND * 2);
  u16*   we1p = (u16*)take((size_t)NH * NINP * 2);   // tiled
  u16*   we2b = (u16*)take((size_t)NH * NH * 2);     // tiled
  u16*   we3p = (u16*)take((size_t)256 * NH * 2);    // tiled, rows 64..255 zero
  u16*   wd1b = (u16*)take((size_t)NH * ND * 2);     // row-major (K=64)
  u16*   wd2b = (u16*)take((size_t)NH * NH * 2);     // tiled
  u16*   wd3p = (u16*)take((size_t)NOUTP * NH * 2);  // tiled, rows 784..1023 zero
  u16*   embb = (u16*)take((size_t)NE * ND * 2);     // row-major (K=64)
  float* cvec = (float*)take(NE * 4);
  float* lossa = (float*)take(4);
  float* scores = (float*)hA;

  hipMemsetAsync(lossa, 0, 4, stream);

  cast_tiled4<<<dim3(1, Bn),    256, 0, stream>>>(x,   xpad, Bn,  NIN, NINP);
  cast_tiled4<<<dim3(1, NH),    256, 0, stream>>>(We1, we1p, NH,  NIN, NINP);
  cast_tiled4<<<dim3(1, NH),    256, 0, stream>>>(We2, we2b, NH,  NH,  NH);
  cast_tiled4<<<dim3(1, 256),   256, 0, stream>>>(We3, we3p, ND,  NH,  NH);
  cast_rm4  <<<dim3(1, NH),     256, 0, stream>>>(Wd1, wd1b, NH,  ND,  ND);
  cast_tiled4<<<dim3(1, NH),    256, 0, stream>>>(Wd2, wd2b, NH,  NH,  NH);
  cast_tiled4<<<dim3(1, NOUTP), 256, 0, stream>>>(Wd3, wd3p, NIN, NH,  NH);
  emb_prep<<<NE, 64, 0, stream>>>(emb, embb, cvec);

  // encoder
  gemm256<1,1,false><<<512, 512, 0, stream>>>(xpad, we1p, be1, nullptr, hA, Bn, NH, NINP, NH, 4);
  gemm256<1,1,false><<<512, 512, 0, stream>>>(hA, we2b, be2, nullptr, hB, Bn, NH, NH, NH, 4);
  gemm256<0,2,true ><<<128, 512, 0, stream>>>(hB, we3p, be3, zf, zb, Bn, ND, NH, ND, 1);
  // VQ
  gemm_bt<0,0><<<dim3(Bn/128, NE/128), 256, 0, stream>>>(zb, embb, nullptr, scores, nullptr, Bn, NE, ND, NE);
  vq_argmin<<<1024, 256, 0, stream>>>(zf, scores, emb, cvec, qb, lossa, Bn);
  // decoder
  gemm_bt<1,3><<<dim3(Bn/128, NH/128), 256, 0, stream>>>(qb, wd1b, bd1, nullptr, hA, Bn, NH, ND, NH);
  gemm256<1,1,false><<<512, 512, 0, stream>>>(hA, wd2b, bd2, nullptr, hB, Bn, NH, NH, NH, 4);
  gemm256<2,0,true ><<<512, 512, 0, stream>>>(hB, wd3p, bd3, out, nullptr, Bn, NIN, NH, NIN, 4);

  loss_final<<<1, 1, 0, stream>>>(lossa, out_loss, (float)Bn * ND);
}

// Round 5
// 401.958 us; speedup vs baseline: 1.4764x; 1.2348x over previous
//
#include <hip/hip_runtime.h>
#include <stdint.h>
#include <stddef.h>

typedef __bf16 bf16x8 __attribute__((ext_vector_type(8)));
typedef float  f32x4  __attribute__((ext_vector_type(4)));
typedef unsigned short u16;

#define NIN   784
#define NINP  896    // 784 padded to 14*64
#define NH    1024
#define NE    512
#define ND    64
#define NOUTP 1024   // Wd3 rows padded to 4*256

#define SBAR()   __builtin_amdgcn_s_barrier()
#define SCHED0() __builtin_amdgcn_sched_barrier(0)
#define LGKM0()  asm volatile("s_waitcnt lgkmcnt(0)" ::: "memory")
#define VM8()    asm volatile("s_waitcnt vmcnt(8)" ::: "memory")
#define VM0()    asm volatile("s_waitcnt vmcnt(0)" ::: "memory")

// Tiled operand layout (A and B of gemm256):
//   element (r,c) -> block (r>>8)*(Cp>>6)+(c>>6), offset (r&255)*64 + ((((c>>3)&7)^(r&7))<<3) + (c&7)
// 64-wide row-major-swizzled layout (qb, wd1b): r*64 + (((d>>3)^(r&7))<<3) + (d&7)

static __device__ __forceinline__ u16 f2bf(float f) {
  union { float f; unsigned u; } v; v.f = f;
  unsigned r = v.u + 0x7fffu + ((v.u >> 16) & 1u);
  return (u16)(r >> 16);
}
static __device__ __forceinline__ float bf2f(u16 b) {
  union { unsigned u; float f; } v; v.u = ((unsigned)b) << 16; return v.f;
}

static __device__ __forceinline__ size_t tiled_off(int r, int c, int Cp) {
  return ((size_t)(r >> 8) * (Cp >> 6) + (c >> 6)) * 16384
       + ((r & 255) << 6) + (((((c >> 3) & 7) ^ (r & 7))) << 3) + (c & 7);
}

// ---------- cast fp32 -> bf16, row-major ----------
__global__ void cast_rm4(const float* __restrict__ src, u16* __restrict__ dst,
                         int R, int C, int Cp) {
  int r = blockIdx.y;
  int c4 = (blockIdx.x * blockDim.x + threadIdx.x) * 4;
  if (c4 >= Cp) return;
  ushort4 o = {0, 0, 0, 0};
  if (r < R && c4 < C) {
    const float4 v = *(const float4*)&src[(size_t)r * C + c4];
    o.x = f2bf(v.x); o.y = f2bf(v.y); o.z = f2bf(v.z); o.w = f2bf(v.w);
  }
  *(ushort4*)&dst[(size_t)r * Cp + c4] = o;
}

// ---------- cast fp32 -> bf16 into tiled+swizzled layout ----------
__global__ void cast_tiled4(const float* __restrict__ src, u16* __restrict__ dst,
                            int R, int C, int Cp) {
  int r = blockIdx.y;
  int c4 = (blockIdx.x * blockDim.x + threadIdx.x) * 4;
  if (c4 >= Cp) return;
  ushort4 o = {0, 0, 0, 0};
  if (r < R && c4 < C) {
    const float4 v = *(const float4*)&src[(size_t)r * C + c4];
    o.x = f2bf(v.x); o.y = f2bf(v.y); o.z = f2bf(v.z); o.w = f2bf(v.w);
  }
  *(ushort4*)&dst[tiled_off(r, c4, Cp)] = o;
}

// ---------- cast fp32 [R][64] -> bf16 rm64-swizzled ----------
__global__ void cast_rm64swz(const float* __restrict__ src, u16* __restrict__ dst, int R) {
  int r = blockIdx.x;
  int d = threadIdx.x;   // 64
  if (r >= R) return;
  dst[r * 64 + (((d >> 3) ^ (r & 7)) << 3) + (d & 7)] = f2bf(src[r * 64 + d]);
}

// ---------- emb -> bf16 rm64-swizzled + per-code squared norm ----------
__global__ void emb_prep(const float* __restrict__ emb, u16* __restrict__ ebf,
                         float* __restrict__ cvec) {
  int j = blockIdx.x, l = threadIdx.x;
  float v = emb[j * ND + l];
  ebf[j * 64 + (((l >> 3) ^ (j & 7)) << 3) + (l & 7)] = f2bf(v);
  float s = v * v;
  #pragma unroll
  for (int off = 32; off > 0; off >>= 1) s += __shfl_down(s, off);
  if (l == 0) cvec[j] = s;
}

// =========================================================================
// D1 GEMM: 128x128 tile, K=64, A/B in rm64-swizzled layout, output tiled bf16
// via LDS-repack coalesced epilogue.
// =========================================================================
__device__ __forceinline__ void stage_lin16k(const u16* __restrict__ src,
                                             u16* lds, int t) {
  int w = t >> 6;
  #pragma unroll
  for (int i = 0; i < 4; ++i) {
    const u16* g = src + (size_t)((i * 256 + t) << 3);
    u16* l = lds + (size_t)((i * 256 + w * 64) << 3);
    __builtin_amdgcn_global_load_lds((__attribute__((address_space(1))) void*)g,
                                     (__attribute__((address_space(3))) void*)l,
                                     16, 0, 0);
  }
}

__global__ __launch_bounds__(256, 2)
void gemm_d1(const u16* __restrict__ A, const u16* __restrict__ Bm,
             const float* __restrict__ bias, u16* __restrict__ Cb, int Np) {
  __shared__ u16 ls[2][128 * 64];     // 32 KB; reused by epilogue as flat 128x128 tile
  const int t = threadIdx.x;
  const int lane = t & 63;
  const int wave = t >> 6;
  const int wr = wave >> 1, wc = wave & 1;
  const int tm = blockIdx.x, tn = blockIdx.y;
  const int lr = lane & 15, hi = lane >> 4;

  stage_lin16k(A + (size_t)tm * 128 * 64, ls[0], t);
  stage_lin16k(Bm + (size_t)tn * 128 * 64, ls[1], t);
  __syncthreads();

  f32x4 acc[4][4] = {};
  #pragma unroll
  for (int kk = 0; kk < 64; kk += 32) {
    bf16x8 af[4], bfr[4];
    #pragma unroll
    for (int m = 0; m < 4; ++m) {
      int row = wr * 64 + m * 16 + lr;
      int ch = ((kk >> 3) + hi) ^ (row & 7);
      af[m] = *(const bf16x8*)&ls[0][row * 64 + ch * 8];
    }
    #pragma unroll
    for (int n = 0; n < 4; ++n) {
      int row = wc * 64 + n * 16 + lr;
      int ch = ((kk >> 3) + hi) ^ (row & 7);
      bfr[n] = *(const bf16x8*)&ls[1][row * 64 + ch * 8];
    }
    #pragma unroll
    for (int m = 0; m < 4; ++m)
      #pragma unroll
      for (int n = 0; n < 4; ++n)
        acc[m][n] = __builtin_amdgcn_mfma_f32_16x16x32_bf16(af[m], bfr[n], acc[m][n], 0, 0, 0);
  }
  __syncthreads();

  // repack -> LDS in consumer tiled layout: [kt_half][row128][chunk_swz][8]
  u16* lf = &ls[0][0];
  #pragma unroll
  for (int m = 0; m < 4; ++m)
    #pragma unroll
    for (int j = 0; j < 4; ++j) {
      int row = wr * 64 + m * 16 + hi * 4 + j;       // 0..127
      #pragma unroll
      for (int n = 0; n < 4; ++n) {
        int col = wc * 64 + n * 16 + lr;             // 0..127
        float v = fmaxf(acc[m][n][j] + bias[tn * 128 + col], 0.f);
        lf[(col >> 6) * 8192 + row * 64 + ((((col >> 3) & 7) ^ (row & 7)) << 3) + (col & 7)] = f2bf(v);
      }
    }
  __syncthreads();

  u16* dst = Cb + ((size_t)(tm >> 1) * (Np >> 6) + tn * 2) * 16384 + (tm & 1) * 8192;
  #pragma unroll
  for (int it = 0; it < 8; ++it) {
    int idx = it * 256 + t;                          // 16B chunk id, 2048 total
    int kt = idx >> 10, rem = idx & 1023;
    *(int4*)&dst[(size_t)kt * 16384 + rem * 8] = *(const int4*)&lf[idx * 8];
  }
}

// =========================================================================
// 256x256-tile, BK=64, 8-wave, 8-phase GEMM, tiled operands, LDS-repack epilogue.
// =========================================================================
__device__ __forceinline__ void stageL(const u16* __restrict__ src,
                                       u16* dstmat, int w, int lane) {
  #pragma unroll
  for (int i = 0; i < 4; ++i) {
    const u16* g = src + (size_t)((i * 512 + w * 64 + lane) << 3);
    u16* l = dstmat + (size_t)((i * 512 + w * 64) << 3);
    __builtin_amdgcn_global_load_lds((__attribute__((address_space(1))) void*)g,
                                     (__attribute__((address_space(3))) void*)l,
                                     16, 0, 0);
  }
}

template <int S>
__device__ __forceinline__ void ldAT(bf16x8 (&af)[4][2], const u16* mat,
                                     int wr, int lr, int hi) {
  #pragma unroll
  for (int m = 0; m < 4; ++m)
    #pragma unroll
    for (int e = 0; e < 2; ++e) {
      int row = wr * 128 + S * 64 + m * 16 + lr;
      int c = (e * 4 + hi) ^ (lr & 7);
      af[m][e] = *(const bf16x8*)&mat[row * 64 + c * 8];
    }
}

template <int S>
__device__ __forceinline__ void ldBT(bf16x8 (&bq)[2][2][2], const u16* mat,
                                     int wc, int lr, int hi) {
  #pragma unroll
  for (int f = 0; f < 2; ++f)
    #pragma unroll
    for (int e = 0; e < 2; ++e) {
      int row = wc * 64 + S * 32 + f * 16 + lr;
      int c = (e * 4 + hi) ^ (lr & 7);
      bq[S][f][e] = *(const bf16x8*)&mat[row * 64 + c * 8];
    }
}

template <int MS, int NS>
__device__ __forceinline__ void quadT(f32x4 (&acc)[8][4], bf16x8 (&af)[4][2],
                                      bf16x8 (&bq)[2][2][2]) {
  __builtin_amdgcn_s_setprio(1);
  #pragma unroll
  for (int m = 0; m < 4; ++m)
    #pragma unroll
    for (int f = 0; f < 2; ++f)
      #pragma unroll
      for (int e = 0; e < 2; ++e)
        acc[MS * 4 + m][NS * 2 + f] = __builtin_amdgcn_mfma_f32_16x16x32_bf16(
            af[m][e], bq[NS][f][e], acc[MS * 4 + m][NS * 2 + f], 0, 0, 0);
  __builtin_amdgcn_s_setprio(0);
}

template <int STG, int VW>
__device__ __forceinline__ void ktile(f32x4 (&acc)[8][4], bf16x8 (&af)[4][2],
                                      bf16x8 (&bq)[2][2][2],
                                      const u16* lA, const u16* lB,
                                      const u16* stA, const u16* stB,
                                      u16* sdA, u16* sdB,
                                      int w, int lane, int wr, int wc, int lr, int hi) {
  ldAT<0>(af, lA, wr, lr, hi); ldBT<0>(bq, lB, wc, lr, hi);
  SCHED0(); SBAR(); LGKM0(); SCHED0();
  quadT<0, 0>(acc, af, bq);
  SCHED0(); SBAR();
  ldBT<1>(bq, lB, wc, lr, hi);
  SCHED0(); SBAR(); LGKM0(); SCHED0();
  quadT<0, 1>(acc, af, bq);
  SCHED0(); SBAR();
  ldAT<1>(af, lA, wr, lr, hi);
  if (STG) stageL(stB, sdB, w, lane);
  SCHED0(); SBAR(); LGKM0(); SCHED0();
  quadT<1, 1>(acc, af, bq);
  SCHED0(); SBAR();
  if (STG) stageL(stA, sdA, w, lane);
  SCHED0(); SBAR();
  quadT<1, 0>(acc, af, bq);
  SCHED0();
  if (VW == 8) { VM8(); } else if (VW == 0) { VM0(); }
  SCHED0(); SBAR();
}

template <int ACT, int OMODE, bool NCHK>  // OMODE: 0 f32 rm via LDS, 1 bf16 tiled via LDS
__global__ __launch_bounds__(512, 2)
void gemm256(const u16* __restrict__ A, const u16* __restrict__ Bm,
             const float* __restrict__ bias, float* __restrict__ Cf,
             u16* __restrict__ Cb, int M, int N, int K, int ldc, int ntiles) {
  __shared__ __attribute__((aligned(128))) u16 lds[2][2][256 * 64];  // 128 KiB
  const int tid  = threadIdx.x;
  const int lane = tid & 63;
  const int w    = tid >> 6;
  const int wr   = w >> 2, wc = w & 3;
  const int lr   = lane & 15, hi = lane >> 4;

  int nwg = gridDim.x, cpx = nwg >> 3, b = blockIdx.x;
  int sb = (b & 7) * cpx + (b >> 3);
  int tm = sb / ntiles, tn = sb % ntiles;

  const int NT = K >> 6;
  const u16* Ap = A + (size_t)tm * NT * 16384;
  const u16* Bp = Bm + (size_t)tn * NT * 16384;

  f32x4 acc[8][4] = {};
  bf16x8 af[4][2], bq[2][2][2];

  stageL(Ap + 0 * 16384, &lds[0][0][0], w, lane);
  stageL(Bp + 0 * 16384, &lds[0][1][0], w, lane);
  stageL(Ap + 1 * 16384, &lds[1][0][0], w, lane);
  stageL(Bp + 1 * 16384, &lds[1][1][0], w, lane);
  VM8(); SCHED0(); SBAR();

  for (int t = 0; t < NT - 2; ++t) {
    const int bufi = t & 1;
    ktile<1, 8>(acc, af, bq, &lds[bufi][0][0], &lds[bufi][1][0],
                Ap + (size_t)(t + 2) * 16384, Bp + (size_t)(t + 2) * 16384,
                &lds[bufi][0][0], &lds[bufi][1][0], w, lane, wr, wc, lr, hi);
  }
  {
    const int bufi = (NT - 2) & 1;
    ktile<0, 0>(acc, af, bq, &lds[bufi][0][0], &lds[bufi][1][0],
                nullptr, nullptr, nullptr, nullptr, w, lane, wr, wc, lr, hi);
  }
  {
    const int bufi = (NT - 1) & 1;
    ktile<0, -1>(acc, af, bq, &lds[bufi][0][0], &lds[bufi][1][0],
                 nullptr, nullptr, nullptr, nullptr, w, lane, wr, wc, lr, hi);
  }

  const int c0 = tn * 256 + wc * 64;
  float bv[4];
  #pragma unroll
  for (int n = 0; n < 4; ++n) {
    int col = c0 + n * 16 + lr;
    bv[n] = (!NCHK || col < N) ? bias[col] : 0.f;
  }

  if (OMODE == 1) {
    // repack full 256x256 bf16 tile into LDS in consumer tiled layout, then linear copy
    u16* lf = &lds[0][0][0];
    __syncthreads();
    #pragma unroll
    for (int m = 0; m < 8; ++m)
      #pragma unroll
      for (int j = 0; j < 4; ++j) {
        int row = wr * 128 + m * 16 + hi * 4 + j;    // 0..255 block-local
        #pragma unroll
        for (int n = 0; n < 4; ++n) {
          int col = wc * 64 + n * 16 + lr;           // 0..255 block-local
          float v = acc[m][n][j] + bv[n];
          if (ACT == 1) v = fmaxf(v, 0.f);
          lf[(col >> 6) * 16384 + row * 64 + ((((col >> 3) & 7) ^ (row & 7)) << 3) + (col & 7)] = f2bf(v);
        }
      }
    __syncthreads();
    u16* dst = Cb + ((size_t)tm * (ldc >> 6) + tn * 4) * 16384;
    #pragma unroll
    for (int it = 0; it < 16; ++it) {
      int idx = it * 512 + tid;                      // 16B chunk id, 8192 total
      *(int4*)&dst[idx * 8] = *(const int4*)&lf[idx * 8];
    }
  } else {
    // f32 row-major output via LDS, two 128-row halves
    float* lf = (float*)&lds[0][0][0];               // [128][256] f32 = 128 KB
    #pragma unroll
    for (int h = 0; h < 2; ++h) {
      __syncthreads();
      if (wr == h) {
        #pragma unroll
        for (int m = 0; m < 8; ++m)
          #pragma unroll
          for (int j = 0; j < 4; ++j) {
            int row = m * 16 + hi * 4 + j;           // 0..127
            #pragma unroll
            for (int n = 0; n < 4; ++n) {
              int col = wc * 64 + n * 16 + lr;
              float v = acc[m][n][j] + bv[n];
              if (ACT == 1) v = fmaxf(v, 0.f);
              if (ACT == 2) v = 1.f / (1.f + __expf(-v));
              lf[row * 256 + col] = v;
            }
          }
      }
      __syncthreads();
      #pragma unroll
      for (int it = 0; it < 16; ++it) {
        int idx = it * 512 + tid;                    // float4 id, 8192 total
        int row = idx >> 6, c16 = idx & 63;
        int col = tn * 256 + c16 * 4;
        if (!NCHK || col < N)
          *(float4*)&Cf[(size_t)(tm * 256 + h * 128 + row) * ldc + col] = *(const float4*)&lf[idx * 4];
      }
    }
  }
}

// =========================================================================
// Fused z = hB @ We3^T + be3 ; scores = z @ emb^T ; argmin ; q gather ; loss
// One block = 128 rows. z never leaves the CU.
// =========================================================================
__global__ __launch_bounds__(256, 1)
void z_vq(const u16* __restrict__ Atiled,      // hB tiled, K=1024
          const u16* __restrict__ Wrm,         // We3 row-major [64][1024]
          const float* __restrict__ be3,
          const u16* __restrict__ ebf,         // emb bf16 rm64-swizzled [512][64]
          const float* __restrict__ cvec,
          u16* __restrict__ qb,                // out: rm64-swizzled [M][64]
          float* __restrict__ lossacc) {
  __shared__ u16 lsA[128 * 64];     // 16 KB
  __shared__ u16 lsW[64 * 64];      // 8 KB
  __shared__ u16 embl[512 * 64];    // 64 KB (swizzled rows)
  __shared__ float zls[128 * 68];   // 34.8 KB padded
  __shared__ int bidxl[128];

  const int t = threadIdx.x;
  const int lane = t & 63;
  const int w = t >> 6;
  const int lr = lane & 15, hi = lane >> 4;
  const int tm = blockIdx.x;

  // stage emb (64 KB) up front; drained by first __syncthreads
  #pragma unroll
  for (int i = 0; i < 16; ++i) {
    const u16* g = ebf + (size_t)((i * 256 + t) << 3);
    u16* l = embl + (size_t)((i * 256 + w * 64) << 3);
    __builtin_amdgcn_global_load_lds((__attribute__((address_space(1))) void*)g,
                                     (__attribute__((address_space(3))) void*)l, 16, 0, 0);
  }

  // ---- z GEMM: 128 x 64, K=1024 ----
  f32x4 acc[2][4] = {};
  const size_t abase0 = ((size_t)(tm >> 1) * 16) * 16384 + (size_t)(tm & 1) * 8192;
  for (int kt = 0; kt < 16; ++kt) {
    // A tile: 16 KB contiguous
    #pragma unroll
    for (int i = 0; i < 4; ++i) {
      const u16* g = Atiled + abase0 + (size_t)kt * 16384 + ((i * 256 + t) << 3);
      u16* l = lsA + ((i * 256 + w * 64) << 3);
      __builtin_amdgcn_global_load_lds((__attribute__((address_space(1))) void*)g,
                                       (__attribute__((address_space(3))) void*)l, 16, 0, 0);
    }
    // W tile: 64x64 from row-major, swizzle-baked source
    #pragma unroll
    for (int i = 0; i < 2; ++i) {
      int c = i * 256 + t;
      int row = c >> 3;
      int cp = (c & 7) ^ (row & 7);
      const u16* g = Wrm + (size_t)row * 1024 + kt * 64 + cp * 8;
      u16* l = lsW + ((i * 256 + w * 64) << 3);
      __builtin_amdgcn_global_load_lds((__attribute__((address_space(1))) void*)g,
                                       (__attribute__((address_space(3))) void*)l, 16, 0, 0);
    }
    __syncthreads();
    #pragma unroll
    for (int kk = 0; kk < 64; kk += 32) {
      bf16x8 af[2], bfr[4];
      #pragma unroll
      for (int m = 0; m < 2; ++m) {
        int row = w * 32 + m * 16 + lr;
        int ch = ((kk >> 3) + hi) ^ (row & 7);
        af[m] = *(const bf16x8*)&lsA[row * 64 + ch * 8];
      }
      #pragma unroll
      for (int n = 0; n < 4; ++n) {
        int row = n * 16 + lr;
        int ch = ((kk >> 3) + hi) ^ (row & 7);
        bfr[n] = *(const bf16x8*)&lsW[row * 64 + ch * 8];
      }
      #pragma unroll
      for (int m = 0; m < 2; ++m)
        #pragma unroll
        for (int n = 0; n < 4; ++n)
          acc[m][n] = __builtin_amdgcn_mfma_f32_16x16x32_bf16(af[m], bfr[n], acc[m][n], 0, 0, 0);
    }
    __syncthreads();
  }

  // ---- z += bias; write to zls (f32, padded) ----
  #pragma unroll
  for (int m = 0; m < 2; ++m)
    #pragma unroll
    for (int j = 0; j < 4; ++j) {
      int row = w * 32 + m * 16 + hi * 4 + j;
      #pragma unroll
      for (int n = 0; n < 4; ++n) {
        int col = n * 16 + lr;
        zls[row * 68 + col] = acc[m][n][j] + be3[col];
      }
    }
  __syncthreads();

  // ---- z bf16 A-fragments from zls ----
  bf16x8 azf[2][2];
  #pragma unroll
  for (int rt = 0; rt < 2; ++rt)
    #pragma unroll
    for (int kf = 0; kf < 2; ++kf) {
      int row = w * 32 + rt * 16 + lr;
      union { bf16x8 v; u16 u[8]; } pk;
      #pragma unroll
      for (int e = 0; e < 8; ++e)
        pk.u[e] = f2bf(zls[row * 68 + kf * 32 + hi * 8 + e]);
      azf[rt][kf] = pk.v;
    }

  // ---- scores + running argmin over 512 codes ----
  float bvv[2][4]; int bii[2][4];
  #pragma unroll
  for (int rt = 0; rt < 2; ++rt)
    #pragma unroll
    for (int j = 0; j < 4; ++j) { bvv[rt][j] = 3.4e38f; bii[rt][j] = 0; }

  for (int ct = 0; ct < 32; ++ct) {
    bf16x8 bqf[2];
    #pragma unroll
    for (int kf = 0; kf < 2; ++kf) {
      int row = ct * 16 + lr;
      int ch = (kf * 4 + hi) ^ (row & 7);
      bqf[kf] = *(const bf16x8*)&embl[row * 64 + ch * 8];
    }
    float cv = cvec[ct * 16 + lr];
    #pragma unroll
    for (int rt = 0; rt < 2; ++rt) {
      f32x4 sc = {};
      sc = __builtin_amdgcn_mfma_f32_16x16x32_bf16(azf[rt][0], bqf[0], sc, 0, 0, 0);
      sc = __builtin_amdgcn_mfma_f32_16x16x32_bf16(azf[rt][1], bqf[1], sc, 0, 0, 0);
      int code = ct * 16 + lr;
      #pragma unroll
      for (int j = 0; j < 4; ++j) {
        float d = cv - sc[j];
        if (d < bvv[rt][j]) { bvv[rt][j] = d; bii[rt][j] = code; }
      }
    }
  }
  // reduce across the 16 lanes (lr) of each hi-group
  #pragma unroll
  for (int off = 1; off < 16; off <<= 1) {
    #pragma unroll
    for (int rt = 0; rt < 2; ++rt)
      #pragma unroll
      for (int j = 0; j < 4; ++j) {
        float ov = __shfl_xor(bvv[rt][j], off);
        int   oi = __shfl_xor(bii[rt][j], off);
        if (ov < bvv[rt][j] || (ov == bvv[rt][j] && oi < bii[rt][j])) {
          bvv[rt][j] = ov; bii[rt][j] = oi;
        }
      }
  }
  if (lr == 0) {
    #pragma unroll
    for (int rt = 0; rt < 2; ++rt)
      #pragma unroll
      for (int j = 0; j < 4; ++j)
        bidxl[w * 32 + rt * 16 + hi * 4 + j] = bii[rt][j];
  }
  __syncthreads();

  // ---- q gather, loss partial, qb write ----
  const int gr0 = tm * 128;
  float ls = 0.f;
  #pragma unroll 4
  for (int r8 = 0; r8 < 32; ++r8) {
    int row = w * 32 + r8;
    int bi = bidxl[row];
    u16 qu = embl[bi * 64 + (((lane >> 3) ^ (bi & 7)) << 3) + (lane & 7)];
    float qf = bf2f(qu);
    float d = qf - zls[row * 68 + lane];
    ls += d * d;
    qb[(size_t)(gr0 + row) * 64 + (((lane >> 3) ^ (row & 7)) << 3) + (lane & 7)] = qu;
  }
  #pragma unroll
  for (int off = 32; off > 0; off >>= 1) ls += __shfl_down(ls, off);
  if (lane == 0) atomicAdd(lossacc, ls);
}

__global__ void loss_final(const float* __restrict__ acc, float* __restrict__ o, float denom) {
  o[0] = acc[0] * 1.25f / denom;
}

// ---------- launch ----------
extern "C" void kernel_launch(void* const* d_in, const int* in_sizes, int n_in,
                              void* d_out, int out_size, void* d_ws, size_t ws_size,
                              hipStream_t stream) {
  const float* x   = (const float*)d_in[0];
  const float* emb = (const float*)d_in[1];
  const float* We1 = (const float*)d_in[2];
  const float* be1 = (const float*)d_in[3];
  const float* We2 = (const float*)d_in[4];
  const float* be2 = (const float*)d_in[5];
  const float* We3 = (const float*)d_in[6];
  const float* be3 = (const float*)d_in[7];
  const float* Wd1 = (const float*)d_in[8];
  const float* bd1 = (const float*)d_in[9];
  const float* Wd2 = (const float*)d_in[10];
  const float* bd2 = (const float*)d_in[11];
  const float* Wd3 = (const float*)d_in[12];
  const float* bd3 = (const float*)d_in[13];

  const int Bn = in_sizes[0] / NIN;              // 32768
  float* out = (float*)d_out;
  float* out_loss = out + (size_t)Bn * NIN;

  char* ws = (char*)d_ws;
  size_t off = 0;
  auto take = [&](size_t bytes) { char* p = ws + off; off += (bytes + 255) & ~(size_t)255; return p; };

  u16*   xpad = (u16*)take((size_t)Bn * NINP * 2);   // tiled
  u16*   hA   = (u16*)take((size_t)Bn * NH * 2);     // tiled: h1 -> h3
  u16*   hB   = (u16*)take((size_t)Bn * NH * 2);     // tiled: h2 -> h4
  u16*   qb   = (u16*)take((size_t)Bn * ND * 2);     // rm64-swizzled
  u16*   we1p = (u16*)take((size_t)NH * NINP * 2);   // tiled
  u16*   we2b = (u16*)take((size_t)NH * NH * 2);     // tiled
  u16*   we3r = (u16*)take((size_t)64 * NH * 2);     // row-major [64][1024]
  u16*   wd1b = (u16*)take((size_t)NH * ND * 2);     // rm64-swizzled
  u16*   wd2b = (u16*)take((size_t)NH * NH * 2);     // tiled
  u16*   wd3p = (u16*)take((size_t)NOUTP * NH * 2);  // tiled, rows 784..1023 zero
  u16*   embb = (u16*)take((size_t)NE * ND * 2);     // rm64-swizzled
  float* cvec = (float*)take(NE * 4);
  float* lossa = (float*)take(4);

  hipMemsetAsync(lossa, 0, 4, stream);

  cast_tiled4<<<dim3(1, Bn),    256, 0, stream>>>(x,   xpad, Bn,  NIN, NINP);
  cast_tiled4<<<dim3(1, NH),    256, 0, stream>>>(We1, we1p, NH,  NIN, NINP);
  cast_tiled4<<<dim3(1, NH),    256, 0, stream>>>(We2, we2b, NH,  NH,  NH);
  cast_rm4  <<<dim3(1, 64),     256, 0, stream>>>(We3, we3r, 64,  NH,  NH);
  cast_rm64swz<<<NH, 64, 0, stream>>>(Wd1, wd1b, NH);
  cast_tiled4<<<dim3(1, NH),    256, 0, stream>>>(Wd2, wd2b, NH,  NH,  NH);
  cast_tiled4<<<dim3(1, NOUTP), 256, 0, stream>>>(Wd3, wd3p, NIN, NH,  NH);
  emb_prep<<<NE, 64, 0, stream>>>(emb, embb, cvec);

  // encoder
  gemm256<1,1,false><<<512, 512, 0, stream>>>(xpad, we1p, be1, nullptr, hA, Bn, NH, NINP, NH, 4);
  gemm256<1,1,false><<<512, 512, 0, stream>>>(hA, we2b, be2, nullptr, hB, Bn, NH, NH, NH, 4);
  // fused z + VQ
  z_vq<<<Bn / 128, 256, 0, stream>>>(hB, we3r, be3, embb, cvec, qb, lossa);
  // decoder
  gemm_d1<<<dim3(Bn / 128, NH / 128), 256, 0, stream>>>(qb, wd1b, bd1, hA, NH);
  gemm256<1,1,false><<<512, 512, 0, stream>>>(hA, wd2b, bd2, nullptr, hB, Bn, NH, NH, NH, 4);
  gemm256<2,0,true ><<<512, 512, 0, stream>>>(hB, wd3p, bd3, out, nullptr, Bn, NIN, NH, NIN, 4);

  loss_final<<<1, 1, 0, stream>>>(lossa, out_loss, (float)Bn * ND);
}